// Round 1
// baseline (463.896 us; speedup 1.0000x reference)
//
#include <hip/hip_runtime.h>
#include <cstdint>
#include <cstddef>

typedef __bf16 bf16;
typedef __bf16 bf16x8 __attribute__((ext_vector_type(8)));
typedef float f32x4 __attribute__((ext_vector_type(4)));

#define DEVI static __device__ __forceinline__

// pack two f32 -> two bf16 (RTNE) in one uint
DEVI unsigned int cvt_pk_bf16(float lo, float hi) {
  unsigned int bl = __float_as_uint(lo);
  bl += 0x7fffu + ((bl >> 16) & 1u);
  unsigned int bh = __float_as_uint(hi);
  bh += 0x7fffu + ((bh >> 16) & 1u);
  return (bl >> 16) | (bh & 0xffff0000u);
}
DEVI float bf_lo(unsigned int u) { return __uint_as_float(u << 16); }
DEVI float bf_hi(unsigned int u) { return __uint_as_float(u & 0xffff0000u); }

// ---------------------------------------------------------------------------
// Generic 1024-K GEMM: out = A(2048x1024) @ W(1024x1024) + bias
// EPI 0: bf16 out in (B,H,S,HD) head-major          (q,k projections)
// EPI 1: bf16 out transposed to (B,H,HD,S)          (v projection -> vT)
// EPI 2: f32 out row-major (B*S, E)                 (final projection)
// ---------------------------------------------------------------------------
template<int BM, int EPI, bool ABF16>
__global__ __launch_bounds__(256) void gemm_k(
    const float* __restrict__ Af, const bf16* __restrict__ Ab,
    const float* __restrict__ W, const float* __restrict__ bias,
    float* __restrict__ outf, bf16* __restrict__ outb)
{
  constexpr int BN = 128;
  constexpr int WM = BM / 64;       // waves along M (2 or 1)
  constexpr int WN = 4 / WM;        // waves along N (2 or 4)
  constexpr int WTN = BN / WN;      // wave tile N (64 or 32)
  constexpr int RT = 4, CT = WTN / 16;
  __shared__ bf16 As[BM * 40];      // [row][k] stride 40 (16B-aligned rows)
  __shared__ bf16 Bs[BN * 40];      // [n][k] transposed, xor-swizzled 16B chunks
  const int tid = threadIdx.x;
  const int lane = tid & 63;
  const int wid = tid >> 6;
  const int q4 = lane >> 4, n16 = lane & 15;
  const int wm = wid / WN, wn = wid % WN;
  const int m0 = blockIdx.y * BM, n0 = blockIdx.x * BN;
  f32x4 acc[RT][CT] = {};

  for (int kb = 0; kb < 32; ++kb) {
    const int k0 = kb * 32;
    __syncthreads();
    // ---- stage A tile (BM x 32) ----
    if constexpr (!ABF16) {
      #pragma unroll
      for (int i = 0; i < BM / 32; ++i) {
        int f4 = tid + i * 256;
        int row = f4 >> 3, kq = f4 & 7;
        float4 v = *(const float4*)(Af + (size_t)(m0 + row) * 1024 + k0 + kq * 4);
        unsigned int p0 = cvt_pk_bf16(v.x, v.y);
        unsigned int p1 = cvt_pk_bf16(v.z, v.w);
        *(uint2*)(&As[row * 40 + kq * 4]) = make_uint2(p0, p1);
      }
    } else {
      #pragma unroll
      for (int i = 0; i < BM / 64; ++i) {
        int u4 = tid + i * 256;
        int row = u4 >> 2, kq = u4 & 3;
        *(uint4*)(&As[row * 40 + kq * 8]) =
            *(const uint4*)(Ab + (size_t)(m0 + row) * 1024 + k0 + kq * 8);
      }
    }
    // ---- stage B tile (32 x 128) transposed into [n][k] ----
    #pragma unroll
    for (int gi = 0; gi < 4; ++gi) {
      int task = tid + gi * 256;
      int nl = task & 127, kq = task >> 7;   // kq: 8B chunk index (4 k's)
      const float* wp = W + (size_t)(k0 + kq * 4) * 1024 + n0 + nl;
      float a0 = wp[0], a1 = wp[1024], a2 = wp[2048], a3 = wp[3072];
      unsigned int p0 = cvt_pk_bf16(a0, a1);
      unsigned int p1 = cvt_pk_bf16(a2, a3);
      int fsw = (nl ^ (nl >> 3)) & 3;
      int c16 = (kq >> 1) ^ fsw;             // swizzled 16B chunk
      *(uint2*)(&Bs[nl * 40 + c16 * 8 + (kq & 1) * 4]) = make_uint2(p0, p1);
    }
    __syncthreads();
    // ---- MFMA ----
    bf16x8 af[RT];
    #pragma unroll
    for (int rt = 0; rt < RT; ++rt)
      af[rt] = *(const bf16x8*)(&As[(wm * 64 + rt * 16 + n16) * 40 + q4 * 8]);
    #pragma unroll
    for (int ct = 0; ct < CT; ++ct) {
      int n = wn * WTN + ct * 16 + n16;
      int fsw = (n ^ (n >> 3)) & 3;
      bf16x8 bfr = *(const bf16x8*)(&Bs[n * 40 + ((q4 ^ fsw) * 8)]);
      #pragma unroll
      for (int rt = 0; rt < RT; ++rt)
        acc[rt][ct] = __builtin_amdgcn_mfma_f32_16x16x32_bf16(af[rt], bfr, acc[rt][ct], 0, 0, 0);
    }
  }

  if constexpr (EPI == 0) {
    #pragma unroll
    for (int ct = 0; ct < CT; ++ct) {
      int col = n0 + wn * WTN + ct * 16 + n16;
      float bv = bias[col];
      int h = col >> 6, d = col & 63;
      #pragma unroll
      for (int rt = 0; rt < RT; ++rt) {
        #pragma unroll
        for (int r = 0; r < 4; ++r) {
          int row = m0 + wm * 64 + rt * 16 + q4 * 4 + r;
          int bb = row >> 10, s = row & 1023;
          outb[((((bb * 16 + h) << 10) + s) << 6) + d] = (bf16)(acc[rt][ct][r] + bv);
        }
      }
    }
  } else if constexpr (EPI == 2) {
    #pragma unroll
    for (int ct = 0; ct < CT; ++ct) {
      int col = n0 + wn * WTN + ct * 16 + n16;
      float bv = bias[col];
      #pragma unroll
      for (int rt = 0; rt < RT; ++rt) {
        #pragma unroll
        for (int r = 0; r < 4; ++r) {
          int row = m0 + wm * 64 + rt * 16 + q4 * 4 + r;
          outf[(size_t)row * 1024 + col] = acc[rt][ct][r] + bv;
        }
      }
    }
  } else {  // EPI 1: transpose via LDS, write (B,H,HD,S)
    __shared__ bf16 T[128 * 130];
    #pragma unroll
    for (int ct = 0; ct < CT; ++ct) {
      int col = n0 + wn * WTN + ct * 16 + n16;
      float bv = bias[col];
      #pragma unroll
      for (int rt = 0; rt < RT; ++rt) {
        #pragma unroll
        for (int r = 0; r < 4; ++r) {
          int rl = wm * 64 + rt * 16 + q4 * 4 + r;
          T[rl * 130 + wn * WTN + ct * 16 + n16] = (bf16)(acc[rt][ct][r] + bv);
        }
      }
    }
    __syncthreads();
    for (int i = 0; i < 64; ++i) {
      int flat = tid + i * 256;
      int nl = flat >> 7, sl = flat & 127;
      int col = n0 + nl, row = m0 + sl;
      int bb = row >> 10, s = row & 1023;
      int h = col >> 6, d = col & 63;
      outb[((((bb * 16 + h) << 6) + d) << 10) + s] = T[sl * 130 + nl];
    }
  }
}

// ---------------------------------------------------------------------------
// K2c: per-(b,h,ktile) column sums of v (from vT layout)
// ---------------------------------------------------------------------------
__global__ void vtile_sum_k(const bf16* __restrict__ vT, float* __restrict__ Tsum)
{
  int kt = blockIdx.x, h = blockIdx.y, b = blockIdx.z, d = threadIdx.x;
  const bf16* p = vT + (((size_t)(b * 16 + h) * 64 + d) << 10) + kt * 64;
  float s = 0.f;
  #pragma unroll 8
  for (int i = 0; i < 64; ++i) s += (float)p[i];
  Tsum[((b * 16 + h) * 16 + kt) * 64 + d] = s;
}

// K2d: suffix scan of tile sums -> Vtail[b][h][kt][d], kt in [0,16]
__global__ void vtail_k(const float* __restrict__ Tsum, float* __restrict__ Vtail)
{
  int h = blockIdx.x, b = blockIdx.y, d = threadIdx.x;
  float c = 0.f;
  Vtail[((b * 16 + h) * 17 + 16) * 64 + d] = 0.f;
  for (int kt = 15; kt >= 0; --kt) {
    c += Tsum[((b * 16 + h) * 16 + kt) * 64 + d];
    Vtail[((b * 16 + h) * 17 + kt) * 64 + d] = c;
  }
}

// ---------------------------------------------------------------------------
// K2: logits (masked, scaled) + depthwise 3x3 conv + bias -> compact bf16 tiles
// grid: (256 = qt*16+ct, H, B); tiles with ct > qt+1 are exactly kq_b (skipped)
// ---------------------------------------------------------------------------
__global__ __launch_bounds__(320) void logits_conv_k(
    const bf16* __restrict__ qh, const bf16* __restrict__ kh,
    const float* __restrict__ kq_w, const float* __restrict__ kq_b,
    bf16* __restrict__ conv_out)
{
  const int qt = (int)blockIdx.x >> 4, ct = (int)blockIdx.x & 15;
  if (ct > qt + 1) return;
  const int h = blockIdx.y, b = blockIdx.z;
  const int q0 = qt * 64, c0 = ct * 64;
  __shared__ float Ls[80 * 81];   // logits rows [q0-2,q0+78), cols [c0-1,c0+79)
  const int tid = threadIdx.x;
  const int lane = tid & 63, wid = tid >> 6;   // 5 waves, wave = row-tile
  const int q4 = lane >> 4, n16 = lane & 15;
  const bf16* qb = qh + ((size_t)(b * 16 + h) << 16);
  const bf16* kb = kh + ((size_t)(b * 16 + h) << 16);

  const int ar = q0 - 2 + wid * 16 + n16;
  const int arc = min(max(ar, 0), 1023);
  bf16x8 a0 = *(const bf16x8*)(qb + arc * 64 + q4 * 8);
  bf16x8 a1 = *(const bf16x8*)(qb + arc * 64 + 32 + q4 * 8);
  f32x4 acc[5] = {};
  #pragma unroll
  for (int c5 = 0; c5 < 5; ++c5) {
    int br = c0 - 1 + c5 * 16 + n16;
    int brc = min(max(br, 0), 1023);
    bf16x8 b0 = *(const bf16x8*)(kb + brc * 64 + q4 * 8);
    bf16x8 b1 = *(const bf16x8*)(kb + brc * 64 + 32 + q4 * 8);
    acc[c5] = __builtin_amdgcn_mfma_f32_16x16x32_bf16(a0, b0, acc[c5], 0, 0, 0);
    acc[c5] = __builtin_amdgcn_mfma_f32_16x16x32_bf16(a1, b1, acc[c5], 0, 0, 0);
  }
  #pragma unroll
  for (int c5 = 0; c5 < 5; ++c5) {
    #pragma unroll
    for (int r = 0; r < 4; ++r) {
      int rg = q0 - 2 + wid * 16 + q4 * 4 + r;
      int cg = c0 - 1 + c5 * 16 + n16;
      float v = (cg >= 0 && cg <= rg && cg < 1024) ? acc[c5][r] * 0.125f : 0.f;
      Ls[(wid * 16 + q4 * 4 + r) * 81 + c5 * 16 + n16] = v;
    }
  }
  __syncthreads();
  float w9[9];
  #pragma unroll
  for (int i = 0; i < 9; ++i) w9[i] = kq_w[h * 9 + i];
  const float bb = kq_b[h];
  bf16* tb = conv_out +
      ((size_t)(b * 16 + h) * 151 + (size_t)(qt * (qt + 3) / 2) + ct) * 4096;
  for (int f = tid; f < 4096; f += 320) {
    int r = f >> 6, c = f & 63;
    const float* L = &Ls[r * 81 + c];
    float s = bb
      + w9[0]*L[0]   + w9[1]*L[1]   + w9[2]*L[2]
      + w9[3]*L[81]  + w9[4]*L[82]  + w9[5]*L[83]
      + w9[6]*L[162] + w9[7]*L[163] + w9[8]*L[164];
    tb[f] = (bf16)s;
  }
}

// ---------------------------------------------------------------------------
// K3: online softmax + head-mix + PV + analytic constant tail + DyT
// grid: (qt=16, g=8, b=2), 256 threads; wave w handles (j=w&1, o=w>>1)
// ---------------------------------------------------------------------------
__global__ __launch_bounds__(256) void soft_pv_k(
    const bf16* __restrict__ conv_out, const bf16* __restrict__ vT,
    const float* __restrict__ Vtail,
    const float* __restrict__ mix_w, const float* __restrict__ mix_b,
    const float* __restrict__ kq_b,
    const float* __restrict__ dyt_alpha, const float* __restrict__ dyt_w,
    const float* __restrict__ dyt_b, const float* __restrict__ depth_scale,
    bf16* __restrict__ out_attn)
{
  const int qt = blockIdx.x, g = blockIdx.y, b = blockIdx.z;
  const int q0 = qt * 64;
  const int nkt = min(qt + 2, 16);
  const int Tc = 1024 - nkt * 64;        // # of constant-tail columns
  const int tid = threadIdx.x;
  const int lane = tid & 63, wid = tid >> 6;
  const int q4 = lane >> 4, n16 = lane & 15;
  const int jj = wid & 1, oo = wid >> 1;

  __shared__ __align__(16) char smem[36864];   // Pbuf+Vbuf, reused as Obuf
  bf16* Pb = (bf16*)smem;                       // [2][64*72]
  bf16* Vb = (bf16*)(smem + 18432);             // [2][64*72]
  float* Ob = (float*)smem;                     // [2][64*66] (after k-loop)
  __shared__ float mM[2][64], lL[2][64], aA[2][64], tmax[2][64], tsum[2][64];
  __shared__ float Vt0[2][64], VtN[2][64];

  const float kqbj = kq_b[2 * g + jj];
  if (tid < 128) {
    int j = tid >> 6, r = tid & 63;
    mM[j][r] = (Tc > 0) ? kq_b[2 * g + j] : -__builtin_inff();
    lL[j][r] = 0.f;
    size_t vb = (size_t)(b * 16 + 2 * g + j) * 17 * 64;
    Vt0[j][r] = Vtail[vb + r];
    VtN[j][r] = (Tc > 0) ? Vtail[vb + (size_t)nkt * 64 + r] : 0.f;
  }
  __syncthreads();

  f32x4 acc[4][4] = {};
  for (int kt = 0; kt < nkt; ++kt) {
    unsigned int cv[2][8];
    #pragma unroll
    for (int j = 0; j < 2; ++j) {
      const unsigned int* cp = (const unsigned int*)(conv_out +
        ((size_t)(b * 16 + 2 * g + j) * 151 + (size_t)(qt * (qt + 3) / 2) + kt) * 4096);
      #pragma unroll
      for (int i = 0; i < 8; ++i) cv[j][i] = cp[tid + i * 256];
    }
    // tile row-max (each 32-lane half holds one row)
    #pragma unroll
    for (int j = 0; j < 2; ++j) {
      #pragma unroll
      for (int i = 0; i < 8; ++i) {
        float mx = fmaxf(bf_lo(cv[j][i]), bf_hi(cv[j][i]));
        #pragma unroll
        for (int mk = 1; mk <= 16; mk <<= 1) mx = fmaxf(mx, __shfl_xor(mx, mk));
        if ((lane & 31) == 0) tmax[j][(tid + i * 256) >> 5] = mx;
      }
    }
    __syncthreads();
    if (tid < 128) {
      int j = tid >> 6, r = tid & 63;
      float mo = mM[j][r];
      float mn = fmaxf(mo, tmax[j][r]);
      mM[j][r] = mn;
      aA[j][r] = __expf(mo - mn);
    }
    // stage v tiles (from vT: rows contiguous in s)
    #pragma unroll
    for (int o = 0; o < 2; ++o) {
      const uint4* vp = (const uint4*)(vT + (((size_t)(b * 16 + 2 * g + o) * 64) << 10) + kt * 64);
      #pragma unroll
      for (int i = 0; i < 2; ++i) {
        int u = tid + i * 256;
        int d = u >> 3, off = u & 7;
        *(uint4*)(&Vb[o * 4608 + d * 72 + off * 8]) = vp[(size_t)d * 128 + off];
      }
    }
    __syncthreads();
    // P = exp(conv - m), row sums
    #pragma unroll
    for (int j = 0; j < 2; ++j) {
      #pragma unroll
      for (int i = 0; i < 8; ++i) {
        int u = tid + i * 256;
        int r = u >> 5, cu = u & 31;
        float m = mM[j][r];
        float p0 = __expf(bf_lo(cv[j][i]) - m);
        float p1 = __expf(bf_hi(cv[j][i]) - m);
        *(unsigned int*)(&Pb[j * 4608 + r * 72 + cu * 2]) = cvt_pk_bf16(p0, p1);
        float s = p0 + p1;
        #pragma unroll
        for (int mk = 1; mk <= 16; mk <<= 1) s += __shfl_xor(s, mk);
        if ((lane & 31) == 0) tsum[j][r] = s;
      }
    }
    __syncthreads();
    if (tid < 128) {
      int j = tid >> 6, r = tid & 63;
      lL[j][r] = lL[j][r] * aA[j][r] + tsum[j][r];
    }
    // rescale + PV MFMA
    float al[16];
    #pragma unroll
    for (int rt = 0; rt < 4; ++rt)
      #pragma unroll
      for (int rr = 0; rr < 4; ++rr)
        al[rt * 4 + rr] = aA[jj][rt * 16 + q4 * 4 + rr];
    #pragma unroll
    for (int rt = 0; rt < 4; ++rt)
      #pragma unroll
      for (int ctt = 0; ctt < 4; ++ctt)
        #pragma unroll
        for (int rr = 0; rr < 4; ++rr)
          acc[rt][ctt][rr] *= al[rt * 4 + rr];
    #pragma unroll
    for (int kk = 0; kk < 2; ++kk) {
      bf16x8 af[4], bfv[4];
      #pragma unroll
      for (int rt = 0; rt < 4; ++rt)
        af[rt] = *(const bf16x8*)(&Pb[jj * 4608 + (rt * 16 + n16) * 72 + kk * 32 + q4 * 8]);
      #pragma unroll
      for (int ctt = 0; ctt < 4; ++ctt)
        bfv[ctt] = *(const bf16x8*)(&Vb[oo * 4608 + (ctt * 16 + n16) * 72 + kk * 32 + q4 * 8]);
      #pragma unroll
      for (int rt = 0; rt < 4; ++rt)
        #pragma unroll
        for (int ctt = 0; ctt < 4; ++ctt)
          acc[rt][ctt] = __builtin_amdgcn_mfma_f32_16x16x32_bf16(af[rt], bfv[ctt], acc[rt][ctt], 0, 0, 0);
    }
    __syncthreads();
  }

  // analytic tail: cols >= 64*nkt all equal kq_b
  if (Tc > 0) {
    if (tid < 128) {
      int j = tid >> 6, r = tid & 63;
      lL[j][r] += (float)Tc * __expf(kq_b[2 * g + j] - mM[j][r]);
    }
    float ej[16];
    #pragma unroll
    for (int rt = 0; rt < 4; ++rt)
      #pragma unroll
      for (int rr = 0; rr < 4; ++rr)
        ej[rt * 4 + rr] = __expf(kqbj - mM[jj][rt * 16 + q4 * 4 + rr]);
    #pragma unroll
    for (int rt = 0; rt < 4; ++rt)
      #pragma unroll
      for (int ctt = 0; ctt < 4; ++ctt)
        #pragma unroll
        for (int rr = 0; rr < 4; ++rr)
          acc[rt][ctt][rr] += ej[rt * 4 + rr] * VtN[oo][ctt * 16 + n16];
  }
  __syncthreads();

  // combine heads: out_o = sum_j mw[o,j] * acc_j / l_j   (Obuf aliases Pb/Vb)
  const float mwj = mix_w[(2 * g + oo) * 2 + jj];
  float fl[16];
  #pragma unroll
  for (int rt = 0; rt < 4; ++rt)
    #pragma unroll
    for (int rr = 0; rr < 4; ++rr)
      fl[rt * 4 + rr] = mwj / lL[jj][rt * 16 + q4 * 4 + rr];
  if (jj == 0) {
    #pragma unroll
    for (int rt = 0; rt < 4; ++rt)
      #pragma unroll
      for (int ctt = 0; ctt < 4; ++ctt)
        #pragma unroll
        for (int rr = 0; rr < 4; ++rr)
          Ob[oo * 4224 + (rt * 16 + q4 * 4 + rr) * 66 + ctt * 16 + n16] =
              fl[rt * 4 + rr] * acc[rt][ctt][rr];
  }
  __syncthreads();
  if (jj == 1) {
    #pragma unroll
    for (int rt = 0; rt < 4; ++rt)
      #pragma unroll
      for (int ctt = 0; ctt < 4; ++ctt)
        #pragma unroll
        for (int rr = 0; rr < 4; ++rr)
          Ob[oo * 4224 + (rt * 16 + q4 * 4 + rr) * 66 + ctt * 16 + n16] +=
              fl[rt * 4 + rr] * acc[rt][ctt][rr];
  }
  __syncthreads();

  const float alpha = dyt_alpha[0];
  const float dsc = depth_scale[0];
  for (int f = tid; f < 8192; f += 256) {
    int o = f >> 12, r = (f >> 6) & 63, d = f & 63;
    float v = Ob[o * 4224 + r * 66 + d] + mix_b[2 * g + o] * Vt0[o][d];
    float e = __expf(2.f * alpha * v);
    float th = 1.f - 2.f / (e + 1.f);
    float y = (th * dyt_w[d] + dyt_b[d]) * dsc;
    out_attn[((size_t)(b * 1024 + q0 + r) << 10) + (2 * g + o) * 64 + d] = (bf16)y;
  }
}

// ---------------------------------------------------------------------------
extern "C" void kernel_launch(void* const* d_in, const int* in_sizes, int n_in,
                              void* d_out, int out_size, void* d_ws, size_t ws_size,
                              hipStream_t stream) {
  const float* Q    = (const float*)d_in[0];
  const float* Kx   = (const float*)d_in[1];
  const float* V    = (const float*)d_in[2];
  const float* Wq   = (const float*)d_in[3];
  const float* bq   = (const float*)d_in[4];
  const float* Wk   = (const float*)d_in[5];
  const float* bk   = (const float*)d_in[6];
  const float* Wv   = (const float*)d_in[7];
  const float* bv   = (const float*)d_in[8];
  const float* Wo   = (const float*)d_in[9];
  const float* bo   = (const float*)d_in[10];
  const float* kq_w = (const float*)d_in[11];
  const float* kq_b = (const float*)d_in[12];
  const float* mixw = (const float*)d_in[13];
  const float* mixb = (const float*)d_in[14];
  const float* dyta = (const float*)d_in[15];
  const float* dytw = (const float*)d_in[16];
  const float* dytb = (const float*)d_in[17];
  const float* dsc  = (const float*)d_in[18];

  char* ws = (char*)d_ws;
  bf16* qh     = (bf16*)(ws);                              // 4 MB
  bf16* kh     = (bf16*)(ws + (size_t)(4  << 20));         // 4 MB
  bf16* vT     = (bf16*)(ws + (size_t)(8  << 20));         // 4 MB (B,H,HD,S)
  bf16* oat    = (bf16*)(ws + (size_t)(12 << 20));         // 4 MB (B,S,E)
  float* Vtail = (float*)(ws + (size_t)(16 << 20));        // 136 KB
  float* Tsum  = (float*)(ws + (size_t)(16 << 20) + (256 << 10)); // 128 KB
  bf16* conv   = (bf16*)(ws + (size_t)(17 << 20));         // 39.6 MB compact

  gemm_k<128, 0, false><<<dim3(8, 16), 256, 0, stream>>>(Q,  nullptr, Wq, bq, nullptr, qh);
  gemm_k<128, 0, false><<<dim3(8, 16), 256, 0, stream>>>(Kx, nullptr, Wk, bk, nullptr, kh);
  gemm_k<128, 1, false><<<dim3(8, 16), 256, 0, stream>>>(V,  nullptr, Wv, bv, nullptr, vT);
  vtile_sum_k<<<dim3(16, 16, 2), 64, 0, stream>>>(vT, Tsum);
  vtail_k<<<dim3(16, 2), 64, 0, stream>>>(Tsum, Vtail);
  logits_conv_k<<<dim3(256, 16, 2), 320, 0, stream>>>(qh, kh, kq_w, kq_b, conv);
  soft_pv_k<<<dim3(16, 8, 2), 256, 0, stream>>>(conv, vT, Vtail, mixw, mixb, kq_b,
                                                dyta, dytw, dytb, dsc, oat);
  gemm_k<64, 2, true><<<dim3(8, 32), 256, 0, stream>>>(nullptr, oat, Wo, bo, (float*)d_out, nullptr);
}

// Round 2
// 368.363 us; speedup vs baseline: 1.2593x; 1.2593x over previous
//
#include <hip/hip_runtime.h>
#include <cstdint>
#include <cstddef>

typedef __bf16 bf16;
typedef __bf16 bf16x8 __attribute__((ext_vector_type(8)));
typedef float f32x4 __attribute__((ext_vector_type(4)));

#define DEVI static __device__ __forceinline__

// pack two f32 -> two bf16 (RTNE) in one uint
DEVI unsigned int cvt_pk_bf16(float lo, float hi) {
  unsigned int bl = __float_as_uint(lo);
  bl += 0x7fffu + ((bl >> 16) & 1u);
  unsigned int bh = __float_as_uint(hi);
  bh += 0x7fffu + ((bh >> 16) & 1u);
  return (bl >> 16) | (bh & 0xffff0000u);
}
DEVI float bf_lo(unsigned int u) { return __uint_as_float(u << 16); }
DEVI float bf_hi(unsigned int u) { return __uint_as_float(u & 0xffff0000u); }

// ---------------------------------------------------------------------------
// Generic 1024-K GEMM: out = A(2048x1024) @ W(1024x1024) + bias
// EPI 0: bf16 out in (B,H,S,HD) head-major          (q,k projections)
// EPI 1: bf16 out transposed to (B,H,HD,S)          (v projection -> vT)
// EPI 2: f32 out row-major (B*S, E)                 (final projection)
// ---------------------------------------------------------------------------
template<int BM, int EPI, bool ABF16>
__global__ __launch_bounds__(256) void gemm_k(
    const float* __restrict__ Af, const bf16* __restrict__ Ab,
    const float* __restrict__ W, const float* __restrict__ bias,
    float* __restrict__ outf, bf16* __restrict__ outb)
{
  constexpr int BN = 128;
  constexpr int WM = BM / 64;       // waves along M (2 or 1)
  constexpr int WN = 4 / WM;        // waves along N (2 or 4)
  constexpr int WTN = BN / WN;      // wave tile N (64 or 32)
  constexpr int RT = 4, CT = WTN / 16;
  __shared__ bf16 As[BM * 40];      // [row][k] stride 40 (16B-aligned rows)
  __shared__ bf16 Bs[BN * 40];      // [n][k] transposed, xor-swizzled 16B chunks
  const int tid = threadIdx.x;
  const int lane = tid & 63;
  const int wid = tid >> 6;
  const int q4 = lane >> 4, n16 = lane & 15;
  const int wm = wid / WN, wn = wid % WN;
  const int m0 = blockIdx.y * BM, n0 = blockIdx.x * BN;
  f32x4 acc[RT][CT] = {};

  for (int kb = 0; kb < 32; ++kb) {
    const int k0 = kb * 32;
    __syncthreads();
    // ---- stage A tile (BM x 32) ----
    if constexpr (!ABF16) {
      #pragma unroll
      for (int i = 0; i < BM / 32; ++i) {
        int f4 = tid + i * 256;
        int row = f4 >> 3, kq = f4 & 7;
        float4 v = *(const float4*)(Af + (size_t)(m0 + row) * 1024 + k0 + kq * 4);
        unsigned int p0 = cvt_pk_bf16(v.x, v.y);
        unsigned int p1 = cvt_pk_bf16(v.z, v.w);
        *(uint2*)(&As[row * 40 + kq * 4]) = make_uint2(p0, p1);
      }
    } else {
      #pragma unroll
      for (int i = 0; i < BM / 64; ++i) {
        int u4 = tid + i * 256;
        int row = u4 >> 2, kq = u4 & 3;
        *(uint4*)(&As[row * 40 + kq * 8]) =
            *(const uint4*)(Ab + (size_t)(m0 + row) * 1024 + k0 + kq * 8);
      }
    }
    // ---- stage B tile (32 x 128) transposed into [n][k] ----
    #pragma unroll
    for (int gi = 0; gi < 4; ++gi) {
      int task = tid + gi * 256;
      int nl = task & 127, kq = task >> 7;   // kq: 8B chunk index (4 k's)
      const float* wp = W + (size_t)(k0 + kq * 4) * 1024 + n0 + nl;
      float a0 = wp[0], a1 = wp[1024], a2 = wp[2048], a3 = wp[3072];
      unsigned int p0 = cvt_pk_bf16(a0, a1);
      unsigned int p1 = cvt_pk_bf16(a2, a3);
      int fsw = (nl ^ (nl >> 3)) & 3;
      int c16 = (kq >> 1) ^ fsw;             // swizzled 16B chunk
      *(uint2*)(&Bs[nl * 40 + c16 * 8 + (kq & 1) * 4]) = make_uint2(p0, p1);
    }
    __syncthreads();
    // ---- MFMA ----
    bf16x8 af[RT];
    #pragma unroll
    for (int rt = 0; rt < RT; ++rt)
      af[rt] = *(const bf16x8*)(&As[(wm * 64 + rt * 16 + n16) * 40 + q4 * 8]);
    #pragma unroll
    for (int ct = 0; ct < CT; ++ct) {
      int n = wn * WTN + ct * 16 + n16;
      int fsw = (n ^ (n >> 3)) & 3;
      bf16x8 bfr = *(const bf16x8*)(&Bs[n * 40 + ((q4 ^ fsw) * 8)]);
      #pragma unroll
      for (int rt = 0; rt < RT; ++rt)
        acc[rt][ct] = __builtin_amdgcn_mfma_f32_16x16x32_bf16(af[rt], bfr, acc[rt][ct], 0, 0, 0);
    }
  }

  if constexpr (EPI == 0) {
    #pragma unroll
    for (int ct = 0; ct < CT; ++ct) {
      int col = n0 + wn * WTN + ct * 16 + n16;
      float bv = bias[col];
      int h = col >> 6, d = col & 63;
      #pragma unroll
      for (int rt = 0; rt < RT; ++rt) {
        #pragma unroll
        for (int r = 0; r < 4; ++r) {
          int row = m0 + wm * 64 + rt * 16 + q4 * 4 + r;
          int bb = row >> 10, s = row & 1023;
          outb[((((bb * 16 + h) << 10) + s) << 6) + d] = (bf16)(acc[rt][ct][r] + bv);
        }
      }
    }
  } else if constexpr (EPI == 2) {
    #pragma unroll
    for (int ct = 0; ct < CT; ++ct) {
      int col = n0 + wn * WTN + ct * 16 + n16;
      float bv = bias[col];
      #pragma unroll
      for (int rt = 0; rt < RT; ++rt) {
        #pragma unroll
        for (int r = 0; r < 4; ++r) {
          int row = m0 + wm * 64 + rt * 16 + q4 * 4 + r;
          outf[(size_t)row * 1024 + col] = acc[rt][ct][r] + bv;
        }
      }
    }
  } else {  // EPI 1: transpose via LDS, write (B,H,HD,S)
    __shared__ bf16 T[128 * 130];
    #pragma unroll
    for (int ct = 0; ct < CT; ++ct) {
      int col = n0 + wn * WTN + ct * 16 + n16;
      float bv = bias[col];
      #pragma unroll
      for (int rt = 0; rt < RT; ++rt) {
        #pragma unroll
        for (int r = 0; r < 4; ++r) {
          int rl = wm * 64 + rt * 16 + q4 * 4 + r;
          T[rl * 130 + wn * WTN + ct * 16 + n16] = (bf16)(acc[rt][ct][r] + bv);
        }
      }
    }
    __syncthreads();
    for (int i = 0; i < 64; ++i) {
      int flat = tid + i * 256;
      int nl = flat >> 7, sl = flat & 127;
      int col = n0 + nl, row = m0 + sl;
      int bb = row >> 10, s = row & 1023;
      int h = col >> 6, d = col & 63;
      outb[((((bb * 16 + h) << 6) + d) << 10) + s] = T[sl * 130 + nl];
    }
  }
}

// ---------------------------------------------------------------------------
// K2c: per-(b,h,ktile) column sums of v (from vT layout)
// ---------------------------------------------------------------------------
__global__ void vtile_sum_k(const bf16* __restrict__ vT, float* __restrict__ Tsum)
{
  int kt = blockIdx.x, h = blockIdx.y, b = blockIdx.z, d = threadIdx.x;
  const bf16* p = vT + (((size_t)(b * 16 + h) * 64 + d) << 10) + kt * 64;
  float s = 0.f;
  #pragma unroll 8
  for (int i = 0; i < 64; ++i) s += (float)p[i];
  Tsum[((b * 16 + h) * 16 + kt) * 64 + d] = s;
}

// K2d: suffix scan of tile sums -> Vtail[b][h][kt][d], kt in [0,16]
__global__ void vtail_k(const float* __restrict__ Tsum, float* __restrict__ Vtail)
{
  int h = blockIdx.x, b = blockIdx.y, d = threadIdx.x;
  float c = 0.f;
  Vtail[((b * 16 + h) * 17 + 16) * 64 + d] = 0.f;
  for (int kt = 15; kt >= 0; --kt) {
    c += Tsum[((b * 16 + h) * 16 + kt) * 64 + d];
    Vtail[((b * 16 + h) * 17 + kt) * 64 + d] = c;
  }
}

// ---------------------------------------------------------------------------
// K2: logits (masked, scaled) + depthwise 3x3 conv + bias -> compact bf16 tiles
// grid: (256 = qt*16+ct, H, B); tiles with ct > qt+1 are exactly kq_b (skipped)
// ---------------------------------------------------------------------------
__global__ __launch_bounds__(320) void logits_conv_k(
    const bf16* __restrict__ qh, const bf16* __restrict__ kh,
    const float* __restrict__ kq_w, const float* __restrict__ kq_b,
    bf16* __restrict__ conv_out)
{
  const int qt = (int)blockIdx.x >> 4, ct = (int)blockIdx.x & 15;
  if (ct > qt + 1) return;
  const int h = blockIdx.y, b = blockIdx.z;
  const int q0 = qt * 64, c0 = ct * 64;
  __shared__ float Ls[80 * 81];   // logits rows [q0-2,q0+78), cols [c0-1,c0+79)
  const int tid = threadIdx.x;
  const int lane = tid & 63, wid = tid >> 6;   // 5 waves, wave = row-tile
  const int q4 = lane >> 4, n16 = lane & 15;
  const bf16* qb = qh + ((size_t)(b * 16 + h) << 16);
  const bf16* kb = kh + ((size_t)(b * 16 + h) << 16);

  const int ar = q0 - 2 + wid * 16 + n16;
  const int arc = min(max(ar, 0), 1023);
  bf16x8 a0 = *(const bf16x8*)(qb + arc * 64 + q4 * 8);
  bf16x8 a1 = *(const bf16x8*)(qb + arc * 64 + 32 + q4 * 8);
  f32x4 acc[5] = {};
  #pragma unroll
  for (int c5 = 0; c5 < 5; ++c5) {
    int br = c0 - 1 + c5 * 16 + n16;
    int brc = min(max(br, 0), 1023);
    bf16x8 b0 = *(const bf16x8*)(kb + brc * 64 + q4 * 8);
    bf16x8 b1 = *(const bf16x8*)(kb + brc * 64 + 32 + q4 * 8);
    acc[c5] = __builtin_amdgcn_mfma_f32_16x16x32_bf16(a0, b0, acc[c5], 0, 0, 0);
    acc[c5] = __builtin_amdgcn_mfma_f32_16x16x32_bf16(a1, b1, acc[c5], 0, 0, 0);
  }
  #pragma unroll
  for (int c5 = 0; c5 < 5; ++c5) {
    #pragma unroll
    for (int r = 0; r < 4; ++r) {
      int rg = q0 - 2 + wid * 16 + q4 * 4 + r;
      int cg = c0 - 1 + c5 * 16 + n16;
      float v = (cg >= 0 && cg <= rg && cg < 1024) ? acc[c5][r] * 0.125f : 0.f;
      Ls[(wid * 16 + q4 * 4 + r) * 81 + c5 * 16 + n16] = v;
    }
  }
  __syncthreads();
  float w9[9];
  #pragma unroll
  for (int i = 0; i < 9; ++i) w9[i] = kq_w[h * 9 + i];
  const float bb = kq_b[h];
  bf16* tb = conv_out +
      ((size_t)(b * 16 + h) * 151 + (size_t)(qt * (qt + 3) / 2) + ct) * 4096;
  for (int f = tid; f < 4096; f += 320) {
    int r = f >> 6, c = f & 63;
    const float* L = &Ls[r * 81 + c];
    float s = bb
      + w9[0]*L[0]   + w9[1]*L[1]   + w9[2]*L[2]
      + w9[3]*L[81]  + w9[4]*L[82]  + w9[5]*L[83]
      + w9[6]*L[162] + w9[7]*L[163] + w9[8]*L[164];
    tb[f] = (bf16)s;
  }
}

// ---------------------------------------------------------------------------
// K3a: per-row softmax stats (max m, inverse denom 1/l) incl. constant tail
// grid: 8192 blocks x 256 (4 waves, 1 wave = 1 row of 32768)
// ---------------------------------------------------------------------------
__global__ __launch_bounds__(256) void rowstat_k(
    const bf16* __restrict__ conv_out, const float* __restrict__ kq_b,
    float* __restrict__ rs)
{
  const int tid = threadIdx.x, lane = tid & 63, wid = tid >> 6;
  const int ridx = blockIdx.x * 4 + wid;            // (b*16+h)*1024 + q
  const int q = ridx & 1023, h = (ridx >> 10) & 15;
  const int qt = q >> 6;
  const int nkt = min(qt + 2, 16);
  const int Tc = 1024 - (nkt << 6);
  const bf16* base = conv_out +
      ((size_t)(ridx >> 10) * 151 + (size_t)(qt * (qt + 3) / 2)) * 4096 + (q & 63) * 64;
  const int nch = nkt * 8;                          // 16B chunks in this row
  uint4 d0 = {0,0,0,0}, d1 = {0,0,0,0};
  const bool v0 = lane < nch, v1 = (lane + 64) < nch;
  if (v0) d0 = *(const uint4*)(base + (size_t)(lane >> 3) * 4096 + (lane & 7) * 8);
  if (v1) {
    int t = lane + 64;
    d1 = *(const uint4*)(base + (size_t)(t >> 3) * 4096 + (t & 7) * 8);
  }
  const unsigned int* p0 = (const unsigned int*)&d0;
  const unsigned int* p1 = (const unsigned int*)&d1;
  float mx = -3.0e38f;
  if (v0) {
    #pragma unroll
    for (int i = 0; i < 4; ++i) mx = fmaxf(mx, fmaxf(bf_lo(p0[i]), bf_hi(p0[i])));
  }
  if (v1) {
    #pragma unroll
    for (int i = 0; i < 4; ++i) mx = fmaxf(mx, fmaxf(bf_lo(p1[i]), bf_hi(p1[i])));
  }
  #pragma unroll
  for (int mk = 1; mk <= 32; mk <<= 1) mx = fmaxf(mx, __shfl_xor(mx, mk));
  const float kb = kq_b[h];
  if (Tc > 0) mx = fmaxf(mx, kb);
  float s = 0.f;
  if (v0) {
    #pragma unroll
    for (int i = 0; i < 4; ++i)
      s += __expf(bf_lo(p0[i]) - mx) + __expf(bf_hi(p0[i]) - mx);
  }
  if (v1) {
    #pragma unroll
    for (int i = 0; i < 4; ++i)
      s += __expf(bf_lo(p1[i]) - mx) + __expf(bf_hi(p1[i]) - mx);
  }
  #pragma unroll
  for (int mk = 1; mk <= 32; mk <<= 1) s += __shfl_xor(s, mk);
  s += (float)Tc * __expf(kb - mx);
  if (lane == 0) {
    rs[(size_t)ridx * 2]     = mx;
    rs[(size_t)ridx * 2 + 1] = 1.f / s;
  }
}

// ---------------------------------------------------------------------------
// K3b: PV with pre-mixed A operand, barrier-free k-loop.
// grid: (qt16=64, g=8, b=2) x 256; wave = (o = wid>>1, khalf = wid&1)
// A_o = sum_j mw[o,j]/l_j * exp(conv_j - m_j); frags straight from global.
// ---------------------------------------------------------------------------
__global__ __launch_bounds__(256) void pv_k(
    const bf16* __restrict__ conv_out, const bf16* __restrict__ vT,
    const float* __restrict__ rs, const float* __restrict__ Vtail,
    const float* __restrict__ mix_w, const float* __restrict__ mix_b,
    const float* __restrict__ kq_b,
    const float* __restrict__ dyt_alpha, const float* __restrict__ dyt_w,
    const float* __restrict__ dyt_b, const float* __restrict__ depth_scale,
    bf16* __restrict__ out_attn)
{
  const int qt16 = blockIdx.x, g = blockIdx.y, b = blockIdx.z;
  const int qt = qt16 >> 2;
  const int nkt = min(qt + 2, 16);
  const int Tc = 1024 - (nkt << 6);
  const int tid = threadIdx.x, lane = tid & 63, wid = tid >> 6;
  const int q4 = lane >> 4, n16 = lane & 15;
  const int oo = wid >> 1, kh = wid & 1;
  const int h0 = 2 * g, ho = h0 + oo;
  const int strow = (qt16 & 3) * 16;

  // per-A-row constants (row = n16 within stripe)
  const int qrow = qt16 * 16 + n16;
  const float2 r0 = *(const float2*)(rs + ((((size_t)(b * 16 + h0)     << 10) + qrow) << 1));
  const float2 r1 = *(const float2*)(rs + ((((size_t)(b * 16 + h0 + 1) << 10) + qrow) << 1));
  const float m0 = r0.x, m1 = r1.x;
  const float w0 = mix_w[ho * 2 + 0] * r0.y;
  const float w1 = mix_w[ho * 2 + 1] * r1.y;

  const bf16* cb0 = conv_out +
      ((size_t)(b * 16 + h0) * 151 + (size_t)(qt * (qt + 3) / 2)) * 4096 + strow * 64 + n16 * 64 + q4 * 8;
  const bf16* cb1 = cb0 + (size_t)151 * 4096;   // head h0+1 plane
  const bf16* vb  = vT + ((size_t)(b * 16 + ho) << 16);

  f32x4 acc[4] = {};
  for (int kt = kh; kt < nkt; kt += 2) {
    uint4 c0[2], c1[2];
    c0[0] = *(const uint4*)(cb0 + (size_t)kt * 4096);
    c0[1] = *(const uint4*)(cb0 + (size_t)kt * 4096 + 32);
    c1[0] = *(const uint4*)(cb1 + (size_t)kt * 4096);
    c1[1] = *(const uint4*)(cb1 + (size_t)kt * 4096 + 32);
    bf16x8 bv[2][4];
    #pragma unroll
    for (int kk = 0; kk < 2; ++kk)
      #pragma unroll
      for (int ct = 0; ct < 4; ++ct)
        bv[kk][ct] = *(const bf16x8*)(vb + (size_t)(ct * 16 + n16) * 1024 + kt * 64 + kk * 32 + q4 * 8);
    #pragma unroll
    for (int kk = 0; kk < 2; ++kk) {
      bf16x8 af;
      const unsigned int* u0 = (const unsigned int*)&c0[kk];
      const unsigned int* u1 = (const unsigned int*)&c1[kk];
      #pragma unroll
      for (int i = 0; i < 4; ++i) {
        float a0 = w0 * __expf(bf_lo(u0[i]) - m0) + w1 * __expf(bf_lo(u1[i]) - m1);
        float a1 = w0 * __expf(bf_hi(u0[i]) - m0) + w1 * __expf(bf_hi(u1[i]) - m1);
        ((unsigned int*)&af)[i] = cvt_pk_bf16(a0, a1);
      }
      #pragma unroll
      for (int ct = 0; ct < 4; ++ct)
        acc[ct] = __builtin_amdgcn_mfma_f32_16x16x32_bf16(af, bv[kk][ct], acc[ct], 0, 0, 0);
    }
  }

  // combine k-parity partials (single barrier in the whole kernel)
  __shared__ float Pp[2][16][64];
  if (kh == 1) {
    #pragma unroll
    for (int ct = 0; ct < 4; ++ct)
      #pragma unroll
      for (int r = 0; r < 4; ++r)
        Pp[oo][q4 * 4 + r][ct * 16 + n16] = acc[ct][r];
  }
  __syncthreads();
  if (kh == 1) return;
  #pragma unroll
  for (int ct = 0; ct < 4; ++ct)
    #pragma unroll
    for (int r = 0; r < 4; ++r)
      acc[ct][r] += Pp[oo][q4 * 4 + r][ct * 16 + n16];

  // epilogue: tail + mix_b*colsum + DyT.  C rows = q4*4+r, cols = ct*16+n16.
  const float kqb0 = kq_b[h0], kqb1 = kq_b[h0 + 1];
  const float mwa = mix_w[ho * 2 + 0], mwb = mix_w[ho * 2 + 1];
  float tw[4];
  #pragma unroll
  for (int r = 0; r < 4; ++r) {
    int qr = qt16 * 16 + q4 * 4 + r;
    float2 s0 = *(const float2*)(rs + ((((size_t)(b * 16 + h0)     << 10) + qr) << 1));
    float2 s1 = *(const float2*)(rs + ((((size_t)(b * 16 + h0 + 1) << 10) + qr) << 1));
    tw[r] = (Tc > 0) ? (mwa * s0.y * __expf(kqb0 - s0.x) +
                        mwb * s1.y * __expf(kqb1 - s1.x)) : 0.f;
  }
  const float mb = mix_b[ho];
  const float alpha = dyt_alpha[0], dsc = depth_scale[0];
  const float* vt = Vtail + (size_t)(b * 16 + ho) * 17 * 64;
  #pragma unroll
  for (int ct = 0; ct < 4; ++ct) {
    int d = ct * 16 + n16;
    float vtn = vt[(size_t)nkt * 64 + d];
    float vt0 = vt[d];
    float wgt = dyt_w[d], bds = dyt_b[d];
    #pragma unroll
    for (int r = 0; r < 4; ++r) {
      float v = acc[ct][r] + tw[r] * vtn + mb * vt0;
      float e = __expf(2.f * alpha * v);
      float th = 1.f - 2.f / (e + 1.f);
      float y = (th * wgt + bds) * dsc;
      int qr = qt16 * 16 + q4 * 4 + r;
      out_attn[(((size_t)(b * 1024 + qr)) << 10) + ho * 64 + d] = (bf16)y;
    }
  }
}

// ---------------------------------------------------------------------------
extern "C" void kernel_launch(void* const* d_in, const int* in_sizes, int n_in,
                              void* d_out, int out_size, void* d_ws, size_t ws_size,
                              hipStream_t stream) {
  const float* Q    = (const float*)d_in[0];
  const float* Kx   = (const float*)d_in[1];
  const float* V    = (const float*)d_in[2];
  const float* Wq   = (const float*)d_in[3];
  const float* bq   = (const float*)d_in[4];
  const float* Wk   = (const float*)d_in[5];
  const float* bk   = (const float*)d_in[6];
  const float* Wv   = (const float*)d_in[7];
  const float* bv   = (const float*)d_in[8];
  const float* Wo   = (const float*)d_in[9];
  const float* bo   = (const float*)d_in[10];
  const float* kq_w = (const float*)d_in[11];
  const float* kq_b = (const float*)d_in[12];
  const float* mixw = (const float*)d_in[13];
  const float* mixb = (const float*)d_in[14];
  const float* dyta = (const float*)d_in[15];
  const float* dytw = (const float*)d_in[16];
  const float* dytb = (const float*)d_in[17];
  const float* dsc  = (const float*)d_in[18];

  char* ws = (char*)d_ws;
  bf16* qh     = (bf16*)(ws);                              // 4 MB
  bf16* kh     = (bf16*)(ws + (size_t)(4  << 20));         // 4 MB
  bf16* vT     = (bf16*)(ws + (size_t)(8  << 20));         // 4 MB (B,H,HD,S)
  bf16* oat    = (bf16*)(ws + (size_t)(12 << 20));         // 4 MB (B,S,E)
  float* Vtail = (float*)(ws + (size_t)(16 << 20));        // 136 KB
  float* Tsum  = (float*)(ws + (size_t)(16 << 20) + (256 << 10)); // 128 KB
  float* rsbuf = (float*)(ws + (size_t)(16 << 20) + (512 << 10)); // 256 KB
  bf16* conv   = (bf16*)(ws + (size_t)(17 << 20));         // 39.6 MB compact

  gemm_k<64, 0, false><<<dim3(8, 32), 256, 0, stream>>>(Q,  nullptr, Wq, bq, nullptr, qh);
  gemm_k<64, 0, false><<<dim3(8, 32), 256, 0, stream>>>(Kx, nullptr, Wk, bk, nullptr, kh);
  gemm_k<128, 1, false><<<dim3(8, 16), 256, 0, stream>>>(V,  nullptr, Wv, bv, nullptr, vT);
  vtile_sum_k<<<dim3(16, 16, 2), 64, 0, stream>>>(vT, Tsum);
  vtail_k<<<dim3(16, 2), 64, 0, stream>>>(Tsum, Vtail);
  logits_conv_k<<<dim3(256, 16, 2), 320, 0, stream>>>(qh, kh, kq_w, kq_b, conv);
  rowstat_k<<<dim3(8192), 256, 0, stream>>>(conv, kq_b, rsbuf);
  pv_k<<<dim3(64, 8, 2), 256, 0, stream>>>(conv, vT, rsbuf, Vtail, mixw, mixb, kq_b,
                                           dyta, dytw, dytb, dsc, oat);
  gemm_k<64, 2, true><<<dim3(8, 32), 256, 0, stream>>>(nullptr, oat, Wo, bo, (float*)d_out, nullptr);
}

// Round 3
// 360.923 us; speedup vs baseline: 1.2853x; 1.0206x over previous
//
#include <hip/hip_runtime.h>
#include <cstdint>
#include <cstddef>

typedef __bf16 bf16;
typedef __bf16 bf16x8 __attribute__((ext_vector_type(8)));
typedef float f32x4 __attribute__((ext_vector_type(4)));

#define DEVI static __device__ __forceinline__

// pack two f32 -> two bf16 (RTNE) in one uint
DEVI unsigned int cvt_pk_bf16(float lo, float hi) {
  unsigned int bl = __float_as_uint(lo);
  bl += 0x7fffu + ((bl >> 16) & 1u);
  unsigned int bh = __float_as_uint(hi);
  bh += 0x7fffu + ((bh >> 16) & 1u);
  return (bl >> 16) | (bh & 0xffff0000u);
}
DEVI float bf_lo(unsigned int u) { return __uint_as_float(u << 16); }
DEVI float bf_hi(unsigned int u) { return __uint_as_float(u & 0xffff0000u); }

// ---------------------------------------------------------------------------
// Generic 1024-K GEMM: out = A(2048x1024) @ W(1024x1024) + bias
// EPI 0: bf16 out in (B,H,S,HD) head-major          (q,k projections)
// EPI 1: bf16 out transposed to (B,H,HD,S)          (v projection -> vT)
// EPI 2: f32 out row-major (B*S, E)                 (final projection)
// ---------------------------------------------------------------------------
template<int BM, int EPI, bool ABF16>
__global__ __launch_bounds__(256) void gemm_k(
    const float* __restrict__ Af, const bf16* __restrict__ Ab,
    const float* __restrict__ W, const float* __restrict__ bias,
    float* __restrict__ outf, bf16* __restrict__ outb)
{
  constexpr int BN = 128;
  constexpr int WM = BM / 64;       // waves along M (2 or 1)
  constexpr int WN = 4 / WM;        // waves along N (2 or 4)
  constexpr int WTN = BN / WN;      // wave tile N (64 or 32)
  constexpr int RT = 4, CT = WTN / 16;
  __shared__ bf16 As[BM * 40];      // [row][k] stride 40 (16B-aligned rows)
  __shared__ bf16 Bs[BN * 40];      // [n][k] transposed, xor-swizzled 16B chunks
  const int tid = threadIdx.x;
  const int lane = tid & 63;
  const int wid = tid >> 6;
  const int q4 = lane >> 4, n16 = lane & 15;
  const int wm = wid / WN, wn = wid % WN;
  const int m0 = blockIdx.y * BM, n0 = blockIdx.x * BN;
  f32x4 acc[RT][CT] = {};

  for (int kb = 0; kb < 32; ++kb) {
    const int k0 = kb * 32;
    __syncthreads();
    // ---- stage A tile (BM x 32) ----
    if constexpr (!ABF16) {
      #pragma unroll
      for (int i = 0; i < BM / 32; ++i) {
        int f4 = tid + i * 256;
        int row = f4 >> 3, kq = f4 & 7;
        float4 v = *(const float4*)(Af + (size_t)(m0 + row) * 1024 + k0 + kq * 4);
        unsigned int p0 = cvt_pk_bf16(v.x, v.y);
        unsigned int p1 = cvt_pk_bf16(v.z, v.w);
        *(uint2*)(&As[row * 40 + kq * 4]) = make_uint2(p0, p1);
      }
    } else {
      #pragma unroll
      for (int i = 0; i < BM / 64; ++i) {
        int u4 = tid + i * 256;
        int row = u4 >> 2, kq = u4 & 3;
        *(uint4*)(&As[row * 40 + kq * 8]) =
            *(const uint4*)(Ab + (size_t)(m0 + row) * 1024 + k0 + kq * 8);
      }
    }
    // ---- stage B tile (32 x 128) transposed into [n][k] ----
    #pragma unroll
    for (int gi = 0; gi < 4; ++gi) {
      int task = tid + gi * 256;
      int nl = task & 127, kq = task >> 7;   // kq: 8B chunk index (4 k's)
      const float* wp = W + (size_t)(k0 + kq * 4) * 1024 + n0 + nl;
      float a0 = wp[0], a1 = wp[1024], a2 = wp[2048], a3 = wp[3072];
      unsigned int p0 = cvt_pk_bf16(a0, a1);
      unsigned int p1 = cvt_pk_bf16(a2, a3);
      int fsw = (nl ^ (nl >> 3)) & 3;
      int c16 = (kq >> 1) ^ fsw;             // swizzled 16B chunk
      *(uint2*)(&Bs[nl * 40 + c16 * 8 + (kq & 1) * 4]) = make_uint2(p0, p1);
    }
    __syncthreads();
    // ---- MFMA ----
    bf16x8 af[RT];
    #pragma unroll
    for (int rt = 0; rt < RT; ++rt)
      af[rt] = *(const bf16x8*)(&As[(wm * 64 + rt * 16 + n16) * 40 + q4 * 8]);
    #pragma unroll
    for (int ct = 0; ct < CT; ++ct) {
      int n = wn * WTN + ct * 16 + n16;
      int fsw = (n ^ (n >> 3)) & 3;
      bf16x8 bfr = *(const bf16x8*)(&Bs[n * 40 + ((q4 ^ fsw) * 8)]);
      #pragma unroll
      for (int rt = 0; rt < RT; ++rt)
        acc[rt][ct] = __builtin_amdgcn_mfma_f32_16x16x32_bf16(af[rt], bfr, acc[rt][ct], 0, 0, 0);
    }
  }

  if constexpr (EPI == 0) {
    #pragma unroll
    for (int ct = 0; ct < CT; ++ct) {
      int col = n0 + wn * WTN + ct * 16 + n16;
      float bv = bias[col];
      int h = col >> 6, d = col & 63;
      #pragma unroll
      for (int rt = 0; rt < RT; ++rt) {
        #pragma unroll
        for (int r = 0; r < 4; ++r) {
          int row = m0 + wm * 64 + rt * 16 + q4 * 4 + r;
          int bb = row >> 10, s = row & 1023;
          outb[((((bb * 16 + h) << 10) + s) << 6) + d] = (bf16)(acc[rt][ct][r] + bv);
        }
      }
    }
  } else if constexpr (EPI == 2) {
    #pragma unroll
    for (int ct = 0; ct < CT; ++ct) {
      int col = n0 + wn * WTN + ct * 16 + n16;
      float bv = bias[col];
      #pragma unroll
      for (int rt = 0; rt < RT; ++rt) {
        #pragma unroll
        for (int r = 0; r < 4; ++r) {
          int row = m0 + wm * 64 + rt * 16 + q4 * 4 + r;
          outf[(size_t)row * 1024 + col] = acc[rt][ct][r] + bv;
        }
      }
    }
  } else {  // EPI 1: transpose via LDS, write (B,H,HD,S)
    __shared__ bf16 T[128 * 130];
    #pragma unroll
    for (int ct = 0; ct < CT; ++ct) {
      int col = n0 + wn * WTN + ct * 16 + n16;
      float bv = bias[col];
      #pragma unroll
      for (int rt = 0; rt < RT; ++rt) {
        #pragma unroll
        for (int r = 0; r < 4; ++r) {
          int rl = wm * 64 + rt * 16 + q4 * 4 + r;
          T[rl * 130 + wn * WTN + ct * 16 + n16] = (bf16)(acc[rt][ct][r] + bv);
        }
      }
    }
    __syncthreads();
    for (int i = 0; i < 64; ++i) {
      int flat = tid + i * 256;
      int nl = flat >> 7, sl = flat & 127;
      int col = n0 + nl, row = m0 + sl;
      int bb = row >> 10, s = row & 1023;
      int h = col >> 6, d = col & 63;
      outb[((((bb * 16 + h) << 6) + d) << 10) + s] = T[sl * 130 + nl];
    }
  }
}

// ---------------------------------------------------------------------------
// K2c: per-(b,h,ktile) column sums of v (from vT layout)
// ---------------------------------------------------------------------------
__global__ void vtile_sum_k(const bf16* __restrict__ vT, float* __restrict__ Tsum)
{
  int kt = blockIdx.x, h = blockIdx.y, b = blockIdx.z, d = threadIdx.x;
  const bf16* p = vT + (((size_t)(b * 16 + h) * 64 + d) << 10) + kt * 64;
  float s = 0.f;
  #pragma unroll 8
  for (int i = 0; i < 64; ++i) s += (float)p[i];
  Tsum[((b * 16 + h) * 16 + kt) * 64 + d] = s;
}

// K2d: suffix scan of tile sums -> Vtail[b][h][kt][d], kt in [0,16]
__global__ void vtail_k(const float* __restrict__ Tsum, float* __restrict__ Vtail)
{
  int h = blockIdx.x, b = blockIdx.y, d = threadIdx.x;
  float c = 0.f;
  Vtail[((b * 16 + h) * 17 + 16) * 64 + d] = 0.f;
  for (int kt = 15; kt >= 0; --kt) {
    c += Tsum[((b * 16 + h) * 16 + kt) * 64 + d];
    Vtail[((b * 16 + h) * 17 + kt) * 64 + d] = c;
  }
}

// ---------------------------------------------------------------------------
// K2: logits (masked, scaled) + depthwise 3x3 conv + bias -> compact bf16
// tiles + per-tile row stats (max, sumexp rel. tile max) for softmax.
// grid: (256 = qt*16+ct, H, B); tiles with ct > qt+1 are exactly kq_b (skipped)
// ---------------------------------------------------------------------------
__global__ __launch_bounds__(320) void logits_conv_k(
    const bf16* __restrict__ qh, const bf16* __restrict__ kh,
    const float* __restrict__ kq_w, const float* __restrict__ kq_b,
    bf16* __restrict__ conv_out, float* __restrict__ tstats)
{
  const int qt = (int)blockIdx.x >> 4, ct = (int)blockIdx.x & 15;
  if (ct > qt + 1) return;
  const int h = blockIdx.y, b = blockIdx.z;
  const int q0 = qt * 64, c0 = ct * 64;
  // stride 84 floats: %4==0 keeps float4 alignment, %8==4 puts the four
  // MFMA-quad row offsets at banks 0/16/0/16 -> pure 2-way (free).
  __shared__ float Ls[80 * 84];   // logits rows [q0-2,q0+78), cols [c0-1,c0+79)
  const int tid = threadIdx.x;
  const int lane = tid & 63, wid = tid >> 6;   // 5 waves, wave = row-tile
  const int q4 = lane >> 4, n16 = lane & 15;
  const bf16* qb = qh + ((size_t)(b * 16 + h) << 16);
  const bf16* kb = kh + ((size_t)(b * 16 + h) << 16);

  const int ar = q0 - 2 + wid * 16 + n16;
  const int arc = min(max(ar, 0), 1023);
  bf16x8 a0 = *(const bf16x8*)(qb + arc * 64 + q4 * 8);
  bf16x8 a1 = *(const bf16x8*)(qb + arc * 64 + 32 + q4 * 8);
  f32x4 acc[5] = {};
  #pragma unroll
  for (int c5 = 0; c5 < 5; ++c5) {
    int br = c0 - 1 + c5 * 16 + n16;
    int brc = min(max(br, 0), 1023);
    bf16x8 b0 = *(const bf16x8*)(kb + brc * 64 + q4 * 8);
    bf16x8 b1 = *(const bf16x8*)(kb + brc * 64 + 32 + q4 * 8);
    acc[c5] = __builtin_amdgcn_mfma_f32_16x16x32_bf16(a0, b0, acc[c5], 0, 0, 0);
    acc[c5] = __builtin_amdgcn_mfma_f32_16x16x32_bf16(a1, b1, acc[c5], 0, 0, 0);
  }
  #pragma unroll
  for (int c5 = 0; c5 < 5; ++c5) {
    #pragma unroll
    for (int r = 0; r < 4; ++r) {
      int rg = q0 - 2 + wid * 16 + q4 * 4 + r;
      int cg = c0 - 1 + c5 * 16 + n16;
      float v = (cg >= 0 && cg <= rg && cg < 1024) ? acc[c5][r] * 0.125f : 0.f;
      Ls[(wid * 16 + q4 * 4 + r) * 84 + c5 * 16 + n16] = v;
    }
  }
  __syncthreads();
  float w9[9];
  #pragma unroll
  for (int i = 0; i < 9; ++i) w9[i] = kq_w[h * 9 + i];
  const float bb = kq_b[h];
  const size_t tplane = (size_t)(b * 16 + h) * 151 + (size_t)(qt * (qt + 3) / 2) + ct;
  bf16* tb = conv_out + tplane * 4096;
  float2* st = (float2*)tstats + tplane * 64;

  // 1024 tasks: task t -> row t>>4, cols (t&15)*4 .. +3. 16-lane groups share
  // a row (base of each wave-iter is a multiple of 64).
  for (int t = tid; t < 1024; t += 320) {
    int r = t >> 4, c4 = (t & 15) * 4;
    const float* L0 = &Ls[r * 84 + c4];
    float rv[3][8];
    #pragma unroll
    for (int dr = 0; dr < 3; ++dr) {
      *(float4*)&rv[dr][0] = *(const float4*)(L0 + dr * 84);
      *(float4*)&rv[dr][4] = *(const float4*)(L0 + dr * 84 + 4);
    }
    float o[4];
    #pragma unroll
    for (int j = 0; j < 4; ++j)
      o[j] = bb + w9[0]*rv[0][j] + w9[1]*rv[0][j+1] + w9[2]*rv[0][j+2]
                + w9[3]*rv[1][j] + w9[4]*rv[1][j+1] + w9[5]*rv[1][j+2]
                + w9[6]*rv[2][j] + w9[7]*rv[2][j+1] + w9[8]*rv[2][j+2];
    unsigned int p0 = cvt_pk_bf16(o[0], o[1]);
    unsigned int p1 = cvt_pk_bf16(o[2], o[3]);
    *(uint2*)(tb + t * 4) = make_uint2(p0, p1);
    // row stats on the bf16-rounded values (exactly what pv_k will exp)
    float v0 = bf_lo(p0), v1 = bf_hi(p0), v2 = bf_lo(p1), v3 = bf_hi(p1);
    float mx = fmaxf(fmaxf(v0, v1), fmaxf(v2, v3));
    #pragma unroll
    for (int mk = 1; mk <= 8; mk <<= 1) mx = fmaxf(mx, __shfl_xor(mx, mk));
    float s = __expf(v0 - mx) + __expf(v1 - mx) + __expf(v2 - mx) + __expf(v3 - mx);
    #pragma unroll
    for (int mk = 1; mk <= 8; mk <<= 1) s += __shfl_xor(s, mk);
    if ((lane & 15) == 0) st[r] = make_float2(mx, s);
  }
}

// ---------------------------------------------------------------------------
// K3a: combine per-tile stats -> per-row (max m, 1/l) incl. constant tail
// 32768 rows, 128 blocks x 256
// ---------------------------------------------------------------------------
__global__ __launch_bounds__(256) void combine_k(
    const float* __restrict__ tstats, const float* __restrict__ kq_b,
    float* __restrict__ rs)
{
  const int ridx = blockIdx.x * 256 + threadIdx.x;
  const int q = ridx & 1023, h = (ridx >> 10) & 15, plane = ridx >> 10;
  const int qt = q >> 6;
  const int nkt = min(qt + 2, 16);
  const int Tc = 1024 - (nkt << 6);
  const float2* ts = (const float2*)tstats +
      ((size_t)plane * 151 + (size_t)(qt * (qt + 3) / 2)) * 64 + (q & 63);
  const float kb = kq_b[h];
  float mx = (Tc > 0) ? kb : -3.0e38f;
  for (int kt = 0; kt < nkt; ++kt) mx = fmaxf(mx, ts[(size_t)kt * 64].x);
  float s = (float)Tc * __expf(kb - mx);
  for (int kt = 0; kt < nkt; ++kt) {
    float2 v = ts[(size_t)kt * 64];
    s += v.y * __expf(v.x - mx);
  }
  rs[(size_t)ridx * 2]     = mx;
  rs[(size_t)ridx * 2 + 1] = 1.f / s;
}

// ---------------------------------------------------------------------------
// K3b: PV with pre-mixed A operand, barrier-free k-loop.
// grid: (qt16=64, g=8, b=2) x 256; wave = (o = wid>>1, khalf = wid&1)
// A_o = sum_j mw[o,j]/l_j * exp(conv_j - m_j); frags straight from global.
// ---------------------------------------------------------------------------
__global__ __launch_bounds__(256) void pv_k(
    const bf16* __restrict__ conv_out, const bf16* __restrict__ vT,
    const float* __restrict__ rs, const float* __restrict__ Vtail,
    const float* __restrict__ mix_w, const float* __restrict__ mix_b,
    const float* __restrict__ kq_b,
    const float* __restrict__ dyt_alpha, const float* __restrict__ dyt_w,
    const float* __restrict__ dyt_b, const float* __restrict__ depth_scale,
    bf16* __restrict__ out_attn)
{
  const int qt16 = blockIdx.x, g = blockIdx.y, b = blockIdx.z;
  const int qt = qt16 >> 2;
  const int nkt = min(qt + 2, 16);
  const int Tc = 1024 - (nkt << 6);
  const int tid = threadIdx.x, lane = tid & 63, wid = tid >> 6;
  const int q4 = lane >> 4, n16 = lane & 15;
  const int oo = wid >> 1, kh = wid & 1;
  const int h0 = 2 * g, ho = h0 + oo;
  const int strow = (qt16 & 3) * 16;

  // per-A-row constants (row = n16 within stripe)
  const int qrow = qt16 * 16 + n16;
  const float2 r0 = *(const float2*)(rs + ((((size_t)(b * 16 + h0)     << 10) + qrow) << 1));
  const float2 r1 = *(const float2*)(rs + ((((size_t)(b * 16 + h0 + 1) << 10) + qrow) << 1));
  const float m0 = r0.x, m1 = r1.x;
  const float w0 = mix_w[ho * 2 + 0] * r0.y;
  const float w1 = mix_w[ho * 2 + 1] * r1.y;

  const bf16* cb0 = conv_out +
      ((size_t)(b * 16 + h0) * 151 + (size_t)(qt * (qt + 3) / 2)) * 4096 + strow * 64 + n16 * 64 + q4 * 8;
  const bf16* cb1 = cb0 + (size_t)151 * 4096;   // head h0+1 plane
  const bf16* vb  = vT + ((size_t)(b * 16 + ho) << 16);

  f32x4 acc[4] = {};
  for (int kt = kh; kt < nkt; kt += 2) {
    uint4 c0[2], c1[2];
    c0[0] = *(const uint4*)(cb0 + (size_t)kt * 4096);
    c0[1] = *(const uint4*)(cb0 + (size_t)kt * 4096 + 32);
    c1[0] = *(const uint4*)(cb1 + (size_t)kt * 4096);
    c1[1] = *(const uint4*)(cb1 + (size_t)kt * 4096 + 32);
    bf16x8 bv[2][4];
    #pragma unroll
    for (int kk = 0; kk < 2; ++kk)
      #pragma unroll
      for (int ct = 0; ct < 4; ++ct)
        bv[kk][ct] = *(const bf16x8*)(vb + (size_t)(ct * 16 + n16) * 1024 + kt * 64 + kk * 32 + q4 * 8);
    #pragma unroll
    for (int kk = 0; kk < 2; ++kk) {
      bf16x8 af;
      const unsigned int* u0 = (const unsigned int*)&c0[kk];
      const unsigned int* u1 = (const unsigned int*)&c1[kk];
      #pragma unroll
      for (int i = 0; i < 4; ++i) {
        float a0 = w0 * __expf(bf_lo(u0[i]) - m0) + w1 * __expf(bf_lo(u1[i]) - m1);
        float a1 = w0 * __expf(bf_hi(u0[i]) - m0) + w1 * __expf(bf_hi(u1[i]) - m1);
        ((unsigned int*)&af)[i] = cvt_pk_bf16(a0, a1);
      }
      #pragma unroll
      for (int ct = 0; ct < 4; ++ct)
        acc[ct] = __builtin_amdgcn_mfma_f32_16x16x32_bf16(af, bv[kk][ct], acc[ct], 0, 0, 0);
    }
  }

  // combine k-parity partials (single barrier in the whole kernel)
  __shared__ float Pp[2][16][64];
  if (kh == 1) {
    #pragma unroll
    for (int ct = 0; ct < 4; ++ct)
      #pragma unroll
      for (int r = 0; r < 4; ++r)
        Pp[oo][q4 * 4 + r][ct * 16 + n16] = acc[ct][r];
  }
  __syncthreads();
  if (kh == 1) return;
  #pragma unroll
  for (int ct = 0; ct < 4; ++ct)
    #pragma unroll
    for (int r = 0; r < 4; ++r)
      acc[ct][r] += Pp[oo][q4 * 4 + r][ct * 16 + n16];

  // epilogue: tail + mix_b*colsum + DyT.  C rows = q4*4+r, cols = ct*16+n16.
  const float kqb0 = kq_b[h0], kqb1 = kq_b[h0 + 1];
  const float mwa = mix_w[ho * 2 + 0], mwb = mix_w[ho * 2 + 1];
  float tw[4];
  #pragma unroll
  for (int r = 0; r < 4; ++r) {
    int qr = qt16 * 16 + q4 * 4 + r;
    float2 s0 = *(const float2*)(rs + ((((size_t)(b * 16 + h0)     << 10) + qr) << 1));
    float2 s1 = *(const float2*)(rs + ((((size_t)(b * 16 + h0 + 1) << 10) + qr) << 1));
    tw[r] = (Tc > 0) ? (mwa * s0.y * __expf(kqb0 - s0.x) +
                        mwb * s1.y * __expf(kqb1 - s1.x)) : 0.f;
  }
  const float mb = mix_b[ho];
  const float alpha = dyt_alpha[0], dsc = depth_scale[0];
  const float* vt = Vtail + (size_t)(b * 16 + ho) * 17 * 64;
  #pragma unroll
  for (int ct = 0; ct < 4; ++ct) {
    int d = ct * 16 + n16;
    float vtn = vt[(size_t)nkt * 64 + d];
    float vt0 = vt[d];
    float wgt = dyt_w[d], bds = dyt_b[d];
    #pragma unroll
    for (int r = 0; r < 4; ++r) {
      float v = acc[ct][r] + tw[r] * vtn + mb * vt0;
      float e = __expf(2.f * alpha * v);
      float th = 1.f - 2.f / (e + 1.f);
      float y = (th * wgt + bds) * dsc;
      int qr = qt16 * 16 + q4 * 4 + r;
      out_attn[(((size_t)(b * 1024 + qr)) << 10) + ho * 64 + d] = (bf16)y;
    }
  }
}

// ---------------------------------------------------------------------------
extern "C" void kernel_launch(void* const* d_in, const int* in_sizes, int n_in,
                              void* d_out, int out_size, void* d_ws, size_t ws_size,
                              hipStream_t stream) {
  const float* Q    = (const float*)d_in[0];
  const float* Kx   = (const float*)d_in[1];
  const float* V    = (const float*)d_in[2];
  const float* Wq   = (const float*)d_in[3];
  const float* bq   = (const float*)d_in[4];
  const float* Wk   = (const float*)d_in[5];
  const float* bk   = (const float*)d_in[6];
  const float* Wv   = (const float*)d_in[7];
  const float* bv   = (const float*)d_in[8];
  const float* Wo   = (const float*)d_in[9];
  const float* bo   = (const float*)d_in[10];
  const float* kq_w = (const float*)d_in[11];
  const float* kq_b = (const float*)d_in[12];
  const float* mixw = (const float*)d_in[13];
  const float* mixb = (const float*)d_in[14];
  const float* dyta = (const float*)d_in[15];
  const float* dytw = (const float*)d_in[16];
  const float* dytb = (const float*)d_in[17];
  const float* dsc  = (const float*)d_in[18];

  char* ws = (char*)d_ws;
  bf16* qh     = (bf16*)(ws);                              // 4 MB
  bf16* kh     = (bf16*)(ws + (size_t)(4  << 20));         // 4 MB
  bf16* vT     = (bf16*)(ws + (size_t)(8  << 20));         // 4 MB (B,H,HD,S)
  // tstats (2.4 MB) aliases the oat region: dead before pv_k writes oat.
  float* tstat = (float*)(ws + (size_t)(12 << 20));
  bf16* oat    = (bf16*)(ws + (size_t)(12 << 20));         // 4 MB (B,S,E)
  float* Vtail = (float*)(ws + (size_t)(16 << 20));        // 136 KB
  float* Tsum  = (float*)(ws + (size_t)(16 << 20) + (256 << 10)); // 128 KB
  float* rsbuf = (float*)(ws + (size_t)(16 << 20) + (512 << 10)); // 256 KB
  bf16* conv   = (bf16*)(ws + (size_t)(17 << 20));         // 39.6 MB compact

  gemm_k<64, 0, false><<<dim3(8, 32), 256, 0, stream>>>(Q,  nullptr, Wq, bq, nullptr, qh);
  gemm_k<64, 0, false><<<dim3(8, 32), 256, 0, stream>>>(Kx, nullptr, Wk, bk, nullptr, kh);
  gemm_k<128, 1, false><<<dim3(8, 16), 256, 0, stream>>>(V,  nullptr, Wv, bv, nullptr, vT);
  vtile_sum_k<<<dim3(16, 16, 2), 64, 0, stream>>>(vT, Tsum);
  vtail_k<<<dim3(16, 2), 64, 0, stream>>>(Tsum, Vtail);
  logits_conv_k<<<dim3(256, 16, 2), 320, 0, stream>>>(qh, kh, kq_w, kq_b, conv, tstat);
  combine_k<<<dim3(128), 256, 0, stream>>>(tstat, kq_b, rsbuf);
  pv_k<<<dim3(64, 8, 2), 256, 0, stream>>>(conv, vT, rsbuf, Vtail, mixw, mixb, kq_b,
                                           dyta, dytw, dytb, dsc, oat);
  gemm_k<64, 2, true><<<dim3(8, 32), 256, 0, stream>>>(nullptr, oat, Wo, bo, (float*)d_out, nullptr);
}

// Round 4
// 303.143 us; speedup vs baseline: 1.5303x; 1.1906x over previous
//
#include <hip/hip_runtime.h>
#include <cstdint>
#include <cstddef>

typedef __bf16 bf16;
typedef __bf16 bf16x8 __attribute__((ext_vector_type(8)));
typedef float f32x4 __attribute__((ext_vector_type(4)));

#define DEVI static __device__ __forceinline__

// pack two f32 -> two bf16 (RTNE) in one uint
DEVI unsigned int cvt_pk_bf16(float lo, float hi) {
  unsigned int bl = __float_as_uint(lo);
  bl += 0x7fffu + ((bl >> 16) & 1u);
  unsigned int bh = __float_as_uint(hi);
  bh += 0x7fffu + ((bh >> 16) & 1u);
  return (bl >> 16) | (bh & 0xffff0000u);
}
DEVI float bf_lo(unsigned int u) { return __uint_as_float(u << 16); }
DEVI float bf_hi(unsigned int u) { return __uint_as_float(u & 0xffff0000u); }

// ---------------------------------------------------------------------------
// W transpose prepass: W (1024x1024 f32, [k][n]) -> Wt (bf16 [n][k]).
// grid (16,16,4), 256 thr; z selects plane {Wq,Wk,Wv,Wo}.
// ---------------------------------------------------------------------------
__global__ __launch_bounds__(256) void wtr_k(
    const float* __restrict__ Wq, const float* __restrict__ Wk,
    const float* __restrict__ Wv, const float* __restrict__ Wo,
    bf16* __restrict__ Wt)
{
  const int z = blockIdx.z;
  const float* W = (z == 0) ? Wq : (z == 1) ? Wk : (z == 2) ? Wv : Wo;
  bf16* out = Wt + ((size_t)z << 20);
  const int n0 = blockIdx.x * 64, k0 = blockIdx.y * 64;
  __shared__ bf16 Ts[64 * 72];
  const int tid = threadIdx.x;
  #pragma unroll
  for (int i = 0; i < 4; ++i) {
    int t = tid + i * 256;
    int kr = t >> 4, nc = t & 15;
    float4 v = *(const float4*)(W + (size_t)(k0 + kr) * 1024 + n0 + nc * 4);
    Ts[(nc * 4 + 0) * 72 + kr] = (bf16)v.x;
    Ts[(nc * 4 + 1) * 72 + kr] = (bf16)v.y;
    Ts[(nc * 4 + 2) * 72 + kr] = (bf16)v.z;
    Ts[(nc * 4 + 3) * 72 + kr] = (bf16)v.w;
  }
  __syncthreads();
  const int n = tid >> 2, kc = tid & 3;
  *(uint4*)(out + (size_t)(n0 + n) * 1024 + k0 + kc * 16) =
      *(const uint4*)(&Ts[n * 72 + kc * 16]);
  *(uint4*)(out + (size_t)(n0 + n) * 1024 + k0 + kc * 16 + 8) =
      *(const uint4*)(&Ts[n * 72 + kc * 16 + 8]);
}

// ---------------------------------------------------------------------------
// Fused projection GEMM: out = A(2048x1024 f32) @ W + bias, W pre-transposed
// bf16 [n][k]. BM=BN=64, 256 thr (4 waves, each 32x32). grid (16,32,3).
// z=0: Q->qh, z=1: K->kh (B,H,S,HD bf16); z=2: V->vT (B,H,HD,S bf16).
// ---------------------------------------------------------------------------
__global__ __launch_bounds__(256) void proj_gemm_k(
    const float* __restrict__ Q, const float* __restrict__ K,
    const float* __restrict__ V, const bf16* __restrict__ Wt,
    const float* __restrict__ bq, const float* __restrict__ bk,
    const float* __restrict__ bv, bf16* __restrict__ outbase)
{
  const int z = blockIdx.z;
  const float* A = (z == 0) ? Q : (z == 1) ? K : V;
  const bf16* Bt = Wt + ((size_t)z << 20);
  const float* bias = (z == 0) ? bq : (z == 1) ? bk : bv;
  bf16* outb = outbase + ((size_t)z << 21);

  __shared__ __align__(16) char sm[10240];
  bf16* As = (bf16*)sm;            // [64][40]
  bf16* Bs = As + 64 * 40;         // [64][40]
  bf16* T  = (bf16*)sm;            // [64][66] (aliases, used post-loop z==2)

  const int tid = threadIdx.x, lane = tid & 63, wid = tid >> 6;
  const int q4 = lane >> 4, n16 = lane & 15;
  const int wm = wid >> 1, wn = wid & 1;
  const int m0 = blockIdx.y * 64, n0 = blockIdx.x * 64;
  const int brow = tid >> 2, bc = tid & 3;
  f32x4 acc[2][2] = {};

  for (int kb = 0; kb < 32; ++kb) {
    const int k0 = kb * 32;
    __syncthreads();
    #pragma unroll
    for (int i = 0; i < 2; ++i) {
      int t = tid + i * 256;
      int row = t >> 3, c = t & 7;
      float4 v = *(const float4*)(A + (size_t)(m0 + row) * 1024 + k0 + c * 4);
      *(uint2*)(&As[row * 40 + c * 4]) =
          make_uint2(cvt_pk_bf16(v.x, v.y), cvt_pk_bf16(v.z, v.w));
    }
    *(uint4*)(&Bs[brow * 40 + bc * 8]) =
        *(const uint4*)(Bt + (size_t)(n0 + brow) * 1024 + k0 + bc * 8);
    __syncthreads();
    bf16x8 af[2], bfv[2];
    #pragma unroll
    for (int rt = 0; rt < 2; ++rt)
      af[rt] = *(const bf16x8*)(&As[(wm * 32 + rt * 16 + n16) * 40 + q4 * 8]);
    #pragma unroll
    for (int ct = 0; ct < 2; ++ct)
      bfv[ct] = *(const bf16x8*)(&Bs[(wn * 32 + ct * 16 + n16) * 40 + q4 * 8]);
    #pragma unroll
    for (int rt = 0; rt < 2; ++rt)
      #pragma unroll
      for (int ct = 0; ct < 2; ++ct)
        acc[rt][ct] = __builtin_amdgcn_mfma_f32_16x16x32_bf16(af[rt], bfv[ct], acc[rt][ct], 0, 0, 0);
  }

  if (z < 2) {   // (B,H,S,HD)
    #pragma unroll
    for (int ct = 0; ct < 2; ++ct) {
      int col = n0 + wn * 32 + ct * 16 + n16;
      float bvl = bias[col];
      int h = col >> 6, d = col & 63;
      #pragma unroll
      for (int rt = 0; rt < 2; ++rt) {
        #pragma unroll
        for (int r = 0; r < 4; ++r) {
          int row = m0 + wm * 32 + rt * 16 + q4 * 4 + r;
          int b2 = row >> 10, s = row & 1023;
          outb[((size_t)((b2 * 16 + h) * 1024 + s) << 6) + d] =
              (bf16)(acc[rt][ct][r] + bvl);
        }
      }
    }
  } else {       // transpose -> (B,H,HD,S)
    __syncthreads();
    #pragma unroll
    for (int ct = 0; ct < 2; ++ct) {
      int cl = wn * 32 + ct * 16 + n16;
      float bvl = bias[n0 + cl];
      #pragma unroll
      for (int rt = 0; rt < 2; ++rt)
        #pragma unroll
        for (int r = 0; r < 4; ++r) {
          int rl = wm * 32 + rt * 16 + q4 * 4 + r;
          T[rl * 66 + cl] = (bf16)(acc[rt][ct][r] + bvl);
        }
    }
    __syncthreads();
    #pragma unroll
    for (int i = 0; i < 16; ++i) {
      int f = tid + i * 256;
      int nl = f >> 6, sl = f & 63;
      int col = n0 + nl, row = m0 + sl;
      int b2 = row >> 10, s = row & 1023;
      int h = col >> 6, d = col & 63;
      outb[((size_t)((b2 * 16 + h) * 64 + d) << 10) + s] = T[sl * 66 + nl];
    }
  }
}

// ---------------------------------------------------------------------------
// Output GEMM: d_out = oat(2048x1024 bf16) @ Wo + bo, WoT bf16 [n][k], f32 out
// ---------------------------------------------------------------------------
__global__ __launch_bounds__(256) void out_gemm_k(
    const bf16* __restrict__ Ab, const bf16* __restrict__ Bt,
    const float* __restrict__ bias, float* __restrict__ outf)
{
  __shared__ __align__(16) char sm[10240];
  bf16* As = (bf16*)sm;
  bf16* Bs = As + 64 * 40;
  const int tid = threadIdx.x, lane = tid & 63, wid = tid >> 6;
  const int q4 = lane >> 4, n16 = lane & 15;
  const int wm = wid >> 1, wn = wid & 1;
  const int m0 = blockIdx.y * 64, n0 = blockIdx.x * 64;
  const int brow = tid >> 2, bc = tid & 3;
  f32x4 acc[2][2] = {};

  for (int kb = 0; kb < 32; ++kb) {
    const int k0 = kb * 32;
    __syncthreads();
    *(uint4*)(&As[brow * 40 + bc * 8]) =
        *(const uint4*)(Ab + (size_t)(m0 + brow) * 1024 + k0 + bc * 8);
    *(uint4*)(&Bs[brow * 40 + bc * 8]) =
        *(const uint4*)(Bt + (size_t)(n0 + brow) * 1024 + k0 + bc * 8);
    __syncthreads();
    bf16x8 af[2], bfv[2];
    #pragma unroll
    for (int rt = 0; rt < 2; ++rt)
      af[rt] = *(const bf16x8*)(&As[(wm * 32 + rt * 16 + n16) * 40 + q4 * 8]);
    #pragma unroll
    for (int ct = 0; ct < 2; ++ct)
      bfv[ct] = *(const bf16x8*)(&Bs[(wn * 32 + ct * 16 + n16) * 40 + q4 * 8]);
    #pragma unroll
    for (int rt = 0; rt < 2; ++rt)
      #pragma unroll
      for (int ct = 0; ct < 2; ++ct)
        acc[rt][ct] = __builtin_amdgcn_mfma_f32_16x16x32_bf16(af[rt], bfv[ct], acc[rt][ct], 0, 0, 0);
  }
  #pragma unroll
  for (int ct = 0; ct < 2; ++ct) {
    int col = n0 + wn * 32 + ct * 16 + n16;
    float bvl = bias[col];
    #pragma unroll
    for (int rt = 0; rt < 2; ++rt)
      #pragma unroll
      for (int r = 0; r < 4; ++r) {
        int row = m0 + wm * 32 + rt * 16 + q4 * 4 + r;
        outf[(size_t)row * 1024 + col] = acc[rt][ct][r] + bvl;
      }
  }
}

// ---------------------------------------------------------------------------
// K2c: per-(b,h,ktile) column sums of v (from vT layout)
// ---------------------------------------------------------------------------
__global__ void vtile_sum_k(const bf16* __restrict__ vT, float* __restrict__ Tsum)
{
  int kt = blockIdx.x, h = blockIdx.y, b = blockIdx.z, d = threadIdx.x;
  const bf16* p = vT + (((size_t)(b * 16 + h) * 64 + d) << 10) + kt * 64;
  float s = 0.f;
  #pragma unroll 8
  for (int i = 0; i < 64; ++i) s += (float)p[i];
  Tsum[((b * 16 + h) * 16 + kt) * 64 + d] = s;
}

// K2d: suffix scan of tile sums -> Vtail[b][h][kt][d], kt in [0,16]
__global__ void vtail_k(const float* __restrict__ Tsum, float* __restrict__ Vtail)
{
  int h = blockIdx.x, b = blockIdx.y, d = threadIdx.x;
  float c = 0.f;
  Vtail[((b * 16 + h) * 17 + 16) * 64 + d] = 0.f;
  for (int kt = 15; kt >= 0; --kt) {
    c += Tsum[((b * 16 + h) * 16 + kt) * 64 + d];
    Vtail[((b * 16 + h) * 17 + kt) * 64 + d] = c;
  }
}

// ---------------------------------------------------------------------------
// K2: logits (masked, scaled) + depthwise 3x3 conv + bias -> compact bf16
// tiles + per-tile row stats. Loads hoisted for ILP; 256-task epilogue.
// ---------------------------------------------------------------------------
__global__ __launch_bounds__(320) void logits_conv_k(
    const bf16* __restrict__ qh, const bf16* __restrict__ kh,
    const float* __restrict__ kq_w, const float* __restrict__ kq_b,
    bf16* __restrict__ conv_out, float* __restrict__ tstats)
{
  const int qt = (int)blockIdx.x >> 4, ct = (int)blockIdx.x & 15;
  if (ct > qt + 1) return;
  const int h = blockIdx.y, b = blockIdx.z;
  const int q0 = qt * 64, c0 = ct * 64;
  __shared__ float Ls[80 * 84];   // rows [q0-2,q0+78), cols [c0-1,c0+79)
  const int tid = threadIdx.x;
  const int lane = tid & 63, wid = tid >> 6;   // 5 waves, wave = 16-row stripe
  const int q4 = lane >> 4, n16 = lane & 15;
  const bf16* qb = qh + ((size_t)(b * 16 + h) << 16);
  const bf16* kb = kh + ((size_t)(b * 16 + h) << 16);

  // ---- hoisted fragment loads (12 x 16B in flight) ----
  const int ar = q0 - 2 + wid * 16 + n16;
  const int arc = min(max(ar, 0), 1023);
  bf16x8 a0 = *(const bf16x8*)(qb + arc * 64 + q4 * 8);
  bf16x8 a1 = *(const bf16x8*)(qb + arc * 64 + 32 + q4 * 8);
  uint4 bl[10];
  #pragma unroll
  for (int c5 = 0; c5 < 5; ++c5) {
    int brc = min(max(c0 - 1 + c5 * 16 + n16, 0), 1023);
    bl[c5 * 2]     = *(const uint4*)(kb + brc * 64 + q4 * 8);
    bl[c5 * 2 + 1] = *(const uint4*)(kb + brc * 64 + 32 + q4 * 8);
  }
  f32x4 acc[5] = {};
  #pragma unroll
  for (int c5 = 0; c5 < 5; ++c5) {
    acc[c5] = __builtin_amdgcn_mfma_f32_16x16x32_bf16(a0, *(const bf16x8*)&bl[c5 * 2],     acc[c5], 0, 0, 0);
    acc[c5] = __builtin_amdgcn_mfma_f32_16x16x32_bf16(a1, *(const bf16x8*)&bl[c5 * 2 + 1], acc[c5], 0, 0, 0);
  }
  #pragma unroll
  for (int c5 = 0; c5 < 5; ++c5) {
    #pragma unroll
    for (int r = 0; r < 4; ++r) {
      int rg = q0 - 2 + wid * 16 + q4 * 4 + r;
      int cg = c0 - 1 + c5 * 16 + n16;
      float v = (cg >= 0 && cg <= rg && cg < 1024) ? acc[c5][r] * 0.125f : 0.f;
      Ls[(wid * 16 + q4 * 4 + r) * 84 + c5 * 16 + n16] = v;
    }
  }
  __syncthreads();

  if (tid < 256) {
    float w9[9];
    #pragma unroll
    for (int i = 0; i < 9; ++i) w9[i] = kq_w[h * 9 + i];
    const float bb = kq_b[h];
    const size_t tplane = (size_t)(b * 16 + h) * 151 + (size_t)(qt * (qt + 3) / 2) + ct;
    bf16* tb = conv_out + tplane * 4096;
    float2* st = (float2*)tstats + tplane * 64;

    const int r = tid >> 2, qr = tid & 3;   // row, 16-col quarter
    float4 R0[5], R1[5], R2[5];
    const float* L0 = &Ls[r * 84 + qr * 16];
    #pragma unroll
    for (int i = 0; i < 5; ++i) {
      R0[i] = *(const float4*)(L0 + i * 4);
      R1[i] = *(const float4*)(L0 + 84 + i * 4);
      R2[i] = *(const float4*)(L0 + 168 + i * 4);
    }
    const float* f0 = (const float*)R0;
    const float* f1 = (const float*)R1;
    const float* f2 = (const float*)R2;
    unsigned int p[8];
    #pragma unroll
    for (int jj = 0; jj < 8; ++jj) {
      float oa = bb + w9[0]*f0[2*jj]   + w9[1]*f0[2*jj+1] + w9[2]*f0[2*jj+2]
                    + w9[3]*f1[2*jj]   + w9[4]*f1[2*jj+1] + w9[5]*f1[2*jj+2]
                    + w9[6]*f2[2*jj]   + w9[7]*f2[2*jj+1] + w9[8]*f2[2*jj+2];
      float ob = bb + w9[0]*f0[2*jj+1] + w9[1]*f0[2*jj+2] + w9[2]*f0[2*jj+3]
                    + w9[3]*f1[2*jj+1] + w9[4]*f1[2*jj+2] + w9[5]*f1[2*jj+3]
                    + w9[6]*f2[2*jj+1] + w9[7]*f2[2*jj+2] + w9[8]*f2[2*jj+3];
      p[jj] = cvt_pk_bf16(oa, ob);
    }
    *(uint4*)(tb + (size_t)r * 64 + qr * 16)     = *(const uint4*)&p[0];
    *(uint4*)(tb + (size_t)r * 64 + qr * 16 + 8) = *(const uint4*)&p[4];
    // row stats on bf16-rounded values (match pv_k exactly)
    float mx = -3.0e38f;
    #pragma unroll
    for (int i = 0; i < 8; ++i) mx = fmaxf(mx, fmaxf(bf_lo(p[i]), bf_hi(p[i])));
    mx = fmaxf(mx, __shfl_xor(mx, 1));
    mx = fmaxf(mx, __shfl_xor(mx, 2));
    float s = 0.f;
    #pragma unroll
    for (int i = 0; i < 8; ++i)
      s += __expf(bf_lo(p[i]) - mx) + __expf(bf_hi(p[i]) - mx);
    s += __shfl_xor(s, 1);
    s += __shfl_xor(s, 2);
    if (qr == 0) st[r] = make_float2(mx, s);
  }
}

// ---------------------------------------------------------------------------
// K3a: combine per-tile stats -> per-row (max m, 1/l) incl. constant tail
// ---------------------------------------------------------------------------
__global__ __launch_bounds__(256) void combine_k(
    const float* __restrict__ tstats, const float* __restrict__ kq_b,
    float* __restrict__ rs)
{
  const int ridx = blockIdx.x * 256 + threadIdx.x;
  const int q = ridx & 1023, h = (ridx >> 10) & 15, plane = ridx >> 10;
  const int qt = q >> 6;
  const int nkt = min(qt + 2, 16);
  const int Tc = 1024 - (nkt << 6);
  const float2* ts = (const float2*)tstats +
      ((size_t)plane * 151 + (size_t)(qt * (qt + 3) / 2)) * 64 + (q & 63);
  const float kb = kq_b[h];
  float mx = (Tc > 0) ? kb : -3.0e38f;
  for (int kt = 0; kt < nkt; ++kt) mx = fmaxf(mx, ts[(size_t)kt * 64].x);
  float s = (float)Tc * __expf(kb - mx);
  for (int kt = 0; kt < nkt; ++kt) {
    float2 v = ts[(size_t)kt * 64];
    s += v.y * __expf(v.x - mx);
  }
  rs[(size_t)ridx * 2]     = mx;
  rs[(size_t)ridx * 2 + 1] = 1.f / s;
}

// ---------------------------------------------------------------------------
// K3b: PV with pre-mixed A operand, barrier-free k-loop.
// ---------------------------------------------------------------------------
__global__ __launch_bounds__(256) void pv_k(
    const bf16* __restrict__ conv_out, const bf16* __restrict__ vT,
    const float* __restrict__ rs, const float* __restrict__ Vtail,
    const float* __restrict__ mix_w, const float* __restrict__ mix_b,
    const float* __restrict__ kq_b,
    const float* __restrict__ dyt_alpha, const float* __restrict__ dyt_w,
    const float* __restrict__ dyt_b, const float* __restrict__ depth_scale,
    bf16* __restrict__ out_attn)
{
  const int qt16 = blockIdx.x, g = blockIdx.y, b = blockIdx.z;
  const int qt = qt16 >> 2;
  const int nkt = min(qt + 2, 16);
  const int Tc = 1024 - (nkt << 6);
  const int tid = threadIdx.x, lane = tid & 63, wid = tid >> 6;
  const int q4 = lane >> 4, n16 = lane & 15;
  const int oo = wid >> 1, kh = wid & 1;
  const int h0 = 2 * g, ho = h0 + oo;
  const int strow = (qt16 & 3) * 16;

  const int qrow = qt16 * 16 + n16;
  const float2 r0 = *(const float2*)(rs + ((((size_t)(b * 16 + h0)     << 10) + qrow) << 1));
  const float2 r1 = *(const float2*)(rs + ((((size_t)(b * 16 + h0 + 1) << 10) + qrow) << 1));
  const float m0 = r0.x, m1 = r1.x;
  const float w0 = mix_w[ho * 2 + 0] * r0.y;
  const float w1 = mix_w[ho * 2 + 1] * r1.y;

  const bf16* cb0 = conv_out +
      ((size_t)(b * 16 + h0) * 151 + (size_t)(qt * (qt + 3) / 2)) * 4096 + strow * 64 + n16 * 64 + q4 * 8;
  const bf16* cb1 = cb0 + (size_t)151 * 4096;
  const bf16* vb  = vT + ((size_t)(b * 16 + ho) << 16);

  f32x4 acc[4] = {};
  for (int kt = kh; kt < nkt; kt += 2) {
    uint4 c0[2], c1[2];
    c0[0] = *(const uint4*)(cb0 + (size_t)kt * 4096);
    c0[1] = *(const uint4*)(cb0 + (size_t)kt * 4096 + 32);
    c1[0] = *(const uint4*)(cb1 + (size_t)kt * 4096);
    c1[1] = *(const uint4*)(cb1 + (size_t)kt * 4096 + 32);
    bf16x8 bv[2][4];
    #pragma unroll
    for (int kk = 0; kk < 2; ++kk)
      #pragma unroll
      for (int ctt = 0; ctt < 4; ++ctt)
        bv[kk][ctt] = *(const bf16x8*)(vb + (size_t)(ctt * 16 + n16) * 1024 + kt * 64 + kk * 32 + q4 * 8);
    #pragma unroll
    for (int kk = 0; kk < 2; ++kk) {
      bf16x8 af;
      const unsigned int* u0 = (const unsigned int*)&c0[kk];
      const unsigned int* u1 = (const unsigned int*)&c1[kk];
      #pragma unroll
      for (int i = 0; i < 4; ++i) {
        float a0 = w0 * __expf(bf_lo(u0[i]) - m0) + w1 * __expf(bf_lo(u1[i]) - m1);
        float a1 = w0 * __expf(bf_hi(u0[i]) - m0) + w1 * __expf(bf_hi(u1[i]) - m1);
        ((unsigned int*)&af)[i] = cvt_pk_bf16(a0, a1);
      }
      #pragma unroll
      for (int ctt = 0; ctt < 4; ++ctt)
        acc[ctt] = __builtin_amdgcn_mfma_f32_16x16x32_bf16(af, bv[kk][ctt], acc[ctt], 0, 0, 0);
    }
  }

  __shared__ float Pp[2][16][64];
  if (kh == 1) {
    #pragma unroll
    for (int ctt = 0; ctt < 4; ++ctt)
      #pragma unroll
      for (int r = 0; r < 4; ++r)
        Pp[oo][q4 * 4 + r][ctt * 16 + n16] = acc[ctt][r];
  }
  __syncthreads();
  if (kh == 1) return;
  #pragma unroll
  for (int ctt = 0; ctt < 4; ++ctt)
    #pragma unroll
    for (int r = 0; r < 4; ++r)
      acc[ctt][r] += Pp[oo][q4 * 4 + r][ctt * 16 + n16];

  const float kqb0 = kq_b[h0], kqb1 = kq_b[h0 + 1];
  const float mwa = mix_w[ho * 2 + 0], mwb = mix_w[ho * 2 + 1];
  float tw[4];
  #pragma unroll
  for (int r = 0; r < 4; ++r) {
    int qr = qt16 * 16 + q4 * 4 + r;
    float2 s0 = *(const float2*)(rs + ((((size_t)(b * 16 + h0)     << 10) + qr) << 1));
    float2 s1 = *(const float2*)(rs + ((((size_t)(b * 16 + h0 + 1) << 10) + qr) << 1));
    tw[r] = (Tc > 0) ? (mwa * s0.y * __expf(kqb0 - s0.x) +
                        mwb * s1.y * __expf(kqb1 - s1.x)) : 0.f;
  }
  const float mb = mix_b[ho];
  const float alpha = dyt_alpha[0], dsc = depth_scale[0];
  const float* vt = Vtail + (size_t)(b * 16 + ho) * 17 * 64;
  #pragma unroll
  for (int ctt = 0; ctt < 4; ++ctt) {
    int d = ctt * 16 + n16;
    float vtn = vt[(size_t)nkt * 64 + d];
    float vt0 = vt[d];
    float wgt = dyt_w[d], bds = dyt_b[d];
    #pragma unroll
    for (int r = 0; r < 4; ++r) {
      float v = acc[ctt][r] + tw[r] * vtn + mb * vt0;
      float e = __expf(2.f * alpha * v);
      float th = 1.f - 2.f / (e + 1.f);
      float y = (th * wgt + bds) * dsc;
      int qr = qt16 * 16 + q4 * 4 + r;
      out_attn[(((size_t)(b * 1024 + qr)) << 10) + ho * 64 + d] = (bf16)y;
    }
  }
}

// ---------------------------------------------------------------------------
extern "C" void kernel_launch(void* const* d_in, const int* in_sizes, int n_in,
                              void* d_out, int out_size, void* d_ws, size_t ws_size,
                              hipStream_t stream) {
  const float* Q    = (const float*)d_in[0];
  const float* Kx   = (const float*)d_in[1];
  const float* V    = (const float*)d_in[2];
  const float* Wq   = (const float*)d_in[3];
  const float* bq   = (const float*)d_in[4];
  const float* Wk   = (const float*)d_in[5];
  const float* bk   = (const float*)d_in[6];
  const float* Wv   = (const float*)d_in[7];
  const float* bv   = (const float*)d_in[8];
  const float* Wo   = (const float*)d_in[9];
  const float* bo   = (const float*)d_in[10];
  const float* kq_w = (const float*)d_in[11];
  const float* kq_b = (const float*)d_in[12];
  const float* mixw = (const float*)d_in[13];
  const float* mixb = (const float*)d_in[14];
  const float* dyta = (const float*)d_in[15];
  const float* dytw = (const float*)d_in[16];
  const float* dytb = (const float*)d_in[17];
  const float* dsc  = (const float*)d_in[18];

  char* ws = (char*)d_ws;
  bf16* qh     = (bf16*)(ws);                              // 4 MB (also kh, vT)
  bf16* kh     = (bf16*)(ws + (size_t)(4  << 20));
  bf16* vT     = (bf16*)(ws + (size_t)(8  << 20));
  float* tstat = (float*)(ws + (size_t)(12 << 20));        // 2.4 MB, aliases oat
  bf16* oat    = (bf16*)(ws + (size_t)(12 << 20));         // 4 MB (B,S,E)
  float* Vtail = (float*)(ws + (size_t)(16 << 20));        // 136 KB
  float* Tsum  = (float*)(ws + (size_t)(16 << 20) + (256 << 10));
  float* rsbuf = (float*)(ws + (size_t)(16 << 20) + (512 << 10));
  bf16* WtT    = (bf16*)(ws + (size_t)(17 << 20));         // 8 MB (4 planes)
  bf16* conv   = (bf16*)(ws + (size_t)(25 << 20));         // 39.6 MB compact

  wtr_k<<<dim3(16, 16, 4), 256, 0, stream>>>(Wq, Wk, Wv, Wo, WtT);
  proj_gemm_k<<<dim3(16, 32, 3), 256, 0, stream>>>(Q, Kx, V, WtT, bq, bk, bv, qh);
  vtile_sum_k<<<dim3(16, 16, 2), 64, 0, stream>>>(vT, Tsum);
  vtail_k<<<dim3(16, 2), 64, 0, stream>>>(Tsum, Vtail);
  logits_conv_k<<<dim3(256, 16, 2), 320, 0, stream>>>(qh, kh, kq_w, kq_b, conv, tstat);
  combine_k<<<dim3(128), 256, 0, stream>>>(tstat, kq_b, rsbuf);
  pv_k<<<dim3(64, 8, 2), 256, 0, stream>>>(conv, vT, rsbuf, Vtail, mixw, mixb, kq_b,
                                           dyta, dytw, dytb, dsc, oat);
  out_gemm_k<<<dim3(16, 32), 256, 0, stream>>>(oat, WtT + ((size_t)3 << 20), bo, (float*)d_out);
}

// Round 5
// 258.055 us; speedup vs baseline: 1.7977x; 1.1747x over previous
//
#include <hip/hip_runtime.h>
#include <cstdint>
#include <cstddef>

typedef __bf16 bf16;
typedef __bf16 bf16x8 __attribute__((ext_vector_type(8)));
typedef float f32x4 __attribute__((ext_vector_type(4)));

#define DEVI static __device__ __forceinline__

// pack two f32 -> two bf16 (RTNE) in one uint
DEVI unsigned int cvt_pk_bf16(float lo, float hi) {
  unsigned int bl = __float_as_uint(lo);
  bl += 0x7fffu + ((bl >> 16) & 1u);
  unsigned int bh = __float_as_uint(hi);
  bh += 0x7fffu + ((bh >> 16) & 1u);
  return (bl >> 16) | (bh & 0xffff0000u);
}
DEVI float bf_lo(unsigned int u) { return __uint_as_float(u << 16); }
DEVI float bf_hi(unsigned int u) { return __uint_as_float(u & 0xffff0000u); }

// ---------------------------------------------------------------------------
// QKV f32 -> bf16 planes (3 x 2048x1024). grid 3072 x 256, 8 elems/thread.
// ---------------------------------------------------------------------------
__global__ __launch_bounds__(256) void cvt_in_k(
    const float* __restrict__ Q, const float* __restrict__ K,
    const float* __restrict__ V, bf16* __restrict__ out)
{
  unsigned t = blockIdx.x * 256 + threadIdx.x;
  int plane = t >> 18;
  size_t off = (size_t)(t & 262143) * 8;
  const float* src = (plane == 0) ? Q : (plane == 1) ? K : V;
  float4 a = *(const float4*)(src + off);
  float4 b = *(const float4*)(src + off + 4);
  uint4 o;
  o.x = cvt_pk_bf16(a.x, a.y); o.y = cvt_pk_bf16(a.z, a.w);
  o.z = cvt_pk_bf16(b.x, b.y); o.w = cvt_pk_bf16(b.z, b.w);
  *(uint4*)(out + ((size_t)plane << 21) + off) = o;
}

// ---------------------------------------------------------------------------
// W transpose prepass: W (1024x1024 f32, [k][n]) -> Wt (bf16 [n][k]).
// ---------------------------------------------------------------------------
__global__ __launch_bounds__(256) void wtr_k(
    const float* __restrict__ Wq, const float* __restrict__ Wk,
    const float* __restrict__ Wv, const float* __restrict__ Wo,
    bf16* __restrict__ Wt)
{
  const int z = blockIdx.z;
  const float* W = (z == 0) ? Wq : (z == 1) ? Wk : (z == 2) ? Wv : Wo;
  bf16* out = Wt + ((size_t)z << 20);
  const int n0 = blockIdx.x * 64, k0 = blockIdx.y * 64;
  __shared__ bf16 Ts[64 * 72];
  const int tid = threadIdx.x;
  #pragma unroll
  for (int i = 0; i < 4; ++i) {
    int t = tid + i * 256;
    int kr = t >> 4, nc = t & 15;
    float4 v = *(const float4*)(W + (size_t)(k0 + kr) * 1024 + n0 + nc * 4);
    Ts[(nc * 4 + 0) * 72 + kr] = (bf16)v.x;
    Ts[(nc * 4 + 1) * 72 + kr] = (bf16)v.y;
    Ts[(nc * 4 + 2) * 72 + kr] = (bf16)v.z;
    Ts[(nc * 4 + 3) * 72 + kr] = (bf16)v.w;
  }
  __syncthreads();
  const int n = tid >> 2, kc = tid & 3;
  *(uint4*)(out + (size_t)(n0 + n) * 1024 + k0 + kc * 16) =
      *(const uint4*)(&Ts[n * 72 + kc * 16]);
  *(uint4*)(out + (size_t)(n0 + n) * 1024 + k0 + kc * 16 + 8) =
      *(const uint4*)(&Ts[n * 72 + kc * 16 + 8]);
}

// ---------------------------------------------------------------------------
// Fused projection GEMM, all-bf16 operands, register-prefetch pipeline.
// grid (16,32,3): z=0 Q->qh, z=1 K->kh, z=2 V->vT(B,H,HD,S).
// ---------------------------------------------------------------------------
__global__ __launch_bounds__(256) void proj_gemm_k(
    const bf16* __restrict__ Abf, const bf16* __restrict__ Wt,
    const float* __restrict__ bq, const float* __restrict__ bk,
    const float* __restrict__ bv, bf16* __restrict__ outbase)
{
  const int z = blockIdx.z;
  const bf16* A  = Abf + ((size_t)z << 21);
  const bf16* Bt = Wt + ((size_t)z << 20);
  const float* bias = (z == 0) ? bq : (z == 1) ? bk : bv;
  bf16* outb = outbase + ((size_t)z << 21);

  __shared__ __align__(16) char sm[10240];
  bf16* As = (bf16*)sm;
  bf16* Bs = As + 64 * 40;
  bf16* T  = (bf16*)sm;

  const int tid = threadIdx.x, lane = tid & 63, wid = tid >> 6;
  const int q4 = lane >> 4, n16 = lane & 15;
  const int wm = wid >> 1, wn = wid & 1;
  const int m0 = blockIdx.y * 64, n0 = blockIdx.x * 64;
  const int brow = tid >> 2, bc = tid & 3;
  f32x4 acc[2][2] = {};

  uint4 aR = *(const uint4*)(A  + (size_t)(m0 + brow) * 1024 + bc * 8);
  uint4 bR = *(const uint4*)(Bt + (size_t)(n0 + brow) * 1024 + bc * 8);
  for (int kb = 0; kb < 32; ++kb) {
    __syncthreads();
    *(uint4*)(&As[brow * 40 + bc * 8]) = aR;
    *(uint4*)(&Bs[brow * 40 + bc * 8]) = bR;
    __syncthreads();
    if (kb < 31) {
      const int k1 = (kb + 1) * 32;
      aR = *(const uint4*)(A  + (size_t)(m0 + brow) * 1024 + k1 + bc * 8);
      bR = *(const uint4*)(Bt + (size_t)(n0 + brow) * 1024 + k1 + bc * 8);
    }
    bf16x8 af[2], bfv[2];
    #pragma unroll
    for (int rt = 0; rt < 2; ++rt)
      af[rt] = *(const bf16x8*)(&As[(wm * 32 + rt * 16 + n16) * 40 + q4 * 8]);
    #pragma unroll
    for (int ct = 0; ct < 2; ++ct)
      bfv[ct] = *(const bf16x8*)(&Bs[(wn * 32 + ct * 16 + n16) * 40 + q4 * 8]);
    #pragma unroll
    for (int rt = 0; rt < 2; ++rt)
      #pragma unroll
      for (int ct = 0; ct < 2; ++ct)
        acc[rt][ct] = __builtin_amdgcn_mfma_f32_16x16x32_bf16(af[rt], bfv[ct], acc[rt][ct], 0, 0, 0);
  }

  if (z < 2) {   // (B,H,S,HD)
    #pragma unroll
    for (int ct = 0; ct < 2; ++ct) {
      int col = n0 + wn * 32 + ct * 16 + n16;
      float bvl = bias[col];
      int h = col >> 6, d = col & 63;
      #pragma unroll
      for (int rt = 0; rt < 2; ++rt) {
        #pragma unroll
        for (int r = 0; r < 4; ++r) {
          int row = m0 + wm * 32 + rt * 16 + q4 * 4 + r;
          int b2 = row >> 10, s = row & 1023;
          outb[((size_t)((b2 * 16 + h) * 1024 + s) << 6) + d] =
              (bf16)(acc[rt][ct][r] + bvl);
        }
      }
    }
  } else {       // transpose -> (B,H,HD,S)
    __syncthreads();
    #pragma unroll
    for (int ct = 0; ct < 2; ++ct) {
      int cl = wn * 32 + ct * 16 + n16;
      float bvl = bias[n0 + cl];
      #pragma unroll
      for (int rt = 0; rt < 2; ++rt)
        #pragma unroll
        for (int r = 0; r < 4; ++r) {
          int rl = wm * 32 + rt * 16 + q4 * 4 + r;
          T[rl * 66 + cl] = (bf16)(acc[rt][ct][r] + bvl);
        }
    }
    __syncthreads();
    #pragma unroll
    for (int i = 0; i < 16; ++i) {
      int f = tid + i * 256;
      int nl = f >> 6, sl = f & 63;
      int col = n0 + nl, row = m0 + sl;
      int b2 = row >> 10, s = row & 1023;
      int h = col >> 6, d = col & 63;
      outb[((size_t)((b2 * 16 + h) * 64 + d) << 10) + s] = T[sl * 66 + nl];
    }
  }
}

// ---------------------------------------------------------------------------
// Output GEMM: d_out = oat(2048x1024 bf16) @ WoT + bo, f32 out. Prefetched.
// ---------------------------------------------------------------------------
__global__ __launch_bounds__(256) void out_gemm_k(
    const bf16* __restrict__ Ab, const bf16* __restrict__ Bt,
    const float* __restrict__ bias, float* __restrict__ outf)
{
  __shared__ __align__(16) char sm[10240];
  bf16* As = (bf16*)sm;
  bf16* Bs = As + 64 * 40;
  const int tid = threadIdx.x, lane = tid & 63, wid = tid >> 6;
  const int q4 = lane >> 4, n16 = lane & 15;
  const int wm = wid >> 1, wn = wid & 1;
  const int m0 = blockIdx.y * 64, n0 = blockIdx.x * 64;
  const int brow = tid >> 2, bc = tid & 3;
  f32x4 acc[2][2] = {};

  uint4 aR = *(const uint4*)(Ab + (size_t)(m0 + brow) * 1024 + bc * 8);
  uint4 bR = *(const uint4*)(Bt + (size_t)(n0 + brow) * 1024 + bc * 8);
  for (int kb = 0; kb < 32; ++kb) {
    __syncthreads();
    *(uint4*)(&As[brow * 40 + bc * 8]) = aR;
    *(uint4*)(&Bs[brow * 40 + bc * 8]) = bR;
    __syncthreads();
    if (kb < 31) {
      const int k1 = (kb + 1) * 32;
      aR = *(const uint4*)(Ab + (size_t)(m0 + brow) * 1024 + k1 + bc * 8);
      bR = *(const uint4*)(Bt + (size_t)(n0 + brow) * 1024 + k1 + bc * 8);
    }
    bf16x8 af[2], bfv[2];
    #pragma unroll
    for (int rt = 0; rt < 2; ++rt)
      af[rt] = *(const bf16x8*)(&As[(wm * 32 + rt * 16 + n16) * 40 + q4 * 8]);
    #pragma unroll
    for (int ct = 0; ct < 2; ++ct)
      bfv[ct] = *(const bf16x8*)(&Bs[(wn * 32 + ct * 16 + n16) * 40 + q4 * 8]);
    #pragma unroll
    for (int rt = 0; rt < 2; ++rt)
      #pragma unroll
      for (int ct = 0; ct < 2; ++ct)
        acc[rt][ct] = __builtin_amdgcn_mfma_f32_16x16x32_bf16(af[rt], bfv[ct], acc[rt][ct], 0, 0, 0);
  }
  #pragma unroll
  for (int ct = 0; ct < 2; ++ct) {
    int col = n0 + wn * 32 + ct * 16 + n16;
    float bvl = bias[col];
    #pragma unroll
    for (int rt = 0; rt < 2; ++rt)
      #pragma unroll
      for (int r = 0; r < 4; ++r) {
        int row = m0 + wm * 32 + rt * 16 + q4 * 4 + r;
        outf[(size_t)row * 1024 + col] = acc[rt][ct][r] + bvl;
      }
  }
}

// ---------------------------------------------------------------------------
// per-(b,h,ktile) column sums of v + suffix scan
// ---------------------------------------------------------------------------
__global__ void vtile_sum_k(const bf16* __restrict__ vT, float* __restrict__ Tsum)
{
  int kt = blockIdx.x, h = blockIdx.y, b = blockIdx.z, d = threadIdx.x;
  const bf16* p = vT + (((size_t)(b * 16 + h) * 64 + d) << 10) + kt * 64;
  float s = 0.f;
  #pragma unroll 8
  for (int i = 0; i < 64; ++i) s += (float)p[i];
  Tsum[((b * 16 + h) * 16 + kt) * 64 + d] = s;
}

__global__ void vtail_k(const float* __restrict__ Tsum, float* __restrict__ Vtail)
{
  int h = blockIdx.x, b = blockIdx.y, d = threadIdx.x;
  float c = 0.f;
  Vtail[((b * 16 + h) * 17 + 16) * 64 + d] = 0.f;
  for (int kt = 15; kt >= 0; --kt) {
    c += Tsum[((b * 16 + h) * 16 + kt) * 64 + d];
    Vtail[((b * 16 + h) * 17 + kt) * 64 + d] = c;
  }
}

// ---------------------------------------------------------------------------
// K2: logits + 3x3 conv -> P = exp(conv - tile_row_max) in bf16, plus
// (mxt, sumP) per tile row. Compact grid: x = linear active-tile index (151).
// ---------------------------------------------------------------------------
__global__ __launch_bounds__(320) void logits_conv_k(
    const bf16* __restrict__ qh, const bf16* __restrict__ kh,
    const float* __restrict__ kq_w, const float* __restrict__ kq_b,
    bf16* __restrict__ conv_out, float* __restrict__ tstats)
{
  // decode (qt, ct) from linear tile index
  const int tt = blockIdx.x;
  int qt = 0, base = 0;
  while (qt < 15 && base + qt + 2 <= tt) { base += qt + 2; ++qt; }
  const int ct = tt - base;
  const int h = blockIdx.y, b = blockIdx.z;
  const int q0 = qt * 64, c0 = ct * 64;
  __shared__ float Ls[66 * 68];   // rows q0-2..q0+63, cols c0-1..c0+64
  const int tid = threadIdx.x;
  const int lane = tid & 63, wid = tid >> 6;   // 5 waves, wave = 16-row stripe
  const int q4 = lane >> 4, n16 = lane & 15;
  const bf16* qb = qh + ((size_t)(b * 16 + h) << 16);
  const bf16* kb = kh + ((size_t)(b * 16 + h) << 16);

  const int ar = q0 - 2 + wid * 16 + n16;
  const int arc = min(max(ar, 0), 1023);
  bf16x8 a0 = *(const bf16x8*)(qb + arc * 64 + q4 * 8);
  bf16x8 a1 = *(const bf16x8*)(qb + arc * 64 + 32 + q4 * 8);
  uint4 bl[10];
  #pragma unroll
  for (int c5 = 0; c5 < 5; ++c5) {
    int brc = min(max(c0 - 1 + c5 * 16 + n16, 0), 1023);
    bl[c5 * 2]     = *(const uint4*)(kb + brc * 64 + q4 * 8);
    bl[c5 * 2 + 1] = *(const uint4*)(kb + brc * 64 + 32 + q4 * 8);
  }
  f32x4 acc[5] = {};
  #pragma unroll
  for (int c5 = 0; c5 < 5; ++c5) {
    acc[c5] = __builtin_amdgcn_mfma_f32_16x16x32_bf16(a0, *(const bf16x8*)&bl[c5 * 2],     acc[c5], 0, 0, 0);
    acc[c5] = __builtin_amdgcn_mfma_f32_16x16x32_bf16(a1, *(const bf16x8*)&bl[c5 * 2 + 1], acc[c5], 0, 0, 0);
  }
  #pragma unroll
  for (int c5 = 0; c5 < 5; ++c5) {
    #pragma unroll
    for (int r = 0; r < 4; ++r) {
      int Lrow = wid * 16 + q4 * 4 + r;
      int Lcol = c5 * 16 + n16;
      if (Lrow < 66 && Lcol < 66) {
        int rg = q0 - 2 + Lrow;
        int cg = c0 - 1 + Lcol;
        float v = (cg >= 0 && cg <= rg) ? acc[c5][r] * 0.125f : 0.f;
        Ls[Lrow * 68 + Lcol] = v;
      }
    }
  }
  __syncthreads();

  if (tid < 256) {
    float w9[9];
    #pragma unroll
    for (int i = 0; i < 9; ++i) w9[i] = kq_w[h * 9 + i];
    const float bb = kq_b[h];
    const size_t tplane = (size_t)(b * 16 + h) * 151 + base + ct;
    bf16* tb = conv_out + tplane * 4096;
    float2* st = (float2*)tstats + tplane * 64;

    const int r = tid >> 2, qr = tid & 3;   // output row, 16-col quarter
    float4 R0[5], R1[5], R2[5];
    const float* L0 = &Ls[r * 68 + qr * 16];
    #pragma unroll
    for (int i = 0; i < 5; ++i) {
      R0[i] = *(const float4*)(L0 + i * 4);
      R1[i] = *(const float4*)(L0 + 68 + i * 4);
      R2[i] = *(const float4*)(L0 + 136 + i * 4);
    }
    const float* f0 = (const float*)R0;
    const float* f1 = (const float*)R1;
    const float* f2 = (const float*)R2;
    float o[16];
    #pragma unroll
    for (int jj = 0; jj < 16; ++jj)
      o[jj] = bb + w9[0]*f0[jj] + w9[1]*f0[jj+1] + w9[2]*f0[jj+2]
                 + w9[3]*f1[jj] + w9[4]*f1[jj+1] + w9[5]*f1[jj+2]
                 + w9[6]*f2[jj] + w9[7]*f2[jj+1] + w9[8]*f2[jj+2];
    // row max across the 4 lanes sharing this row
    float mx = o[0];
    #pragma unroll
    for (int jj = 1; jj < 16; ++jj) mx = fmaxf(mx, o[jj]);
    mx = fmaxf(mx, __shfl_xor(mx, 1));
    mx = fmaxf(mx, __shfl_xor(mx, 2));
    // P = exp(o - mx), rounded to bf16; sum over rounded values
    unsigned int p[8];
    #pragma unroll
    for (int jj = 0; jj < 8; ++jj)
      p[jj] = cvt_pk_bf16(__expf(o[2*jj] - mx), __expf(o[2*jj+1] - mx));
    *(uint4*)(tb + (size_t)r * 64 + qr * 16)     = *(const uint4*)&p[0];
    *(uint4*)(tb + (size_t)r * 64 + qr * 16 + 8) = *(const uint4*)&p[4];
    float s = 0.f;
    #pragma unroll
    for (int jj = 0; jj < 8; ++jj) s += bf_lo(p[jj]) + bf_hi(p[jj]);
    s += __shfl_xor(s, 1);
    s += __shfl_xor(s, 2);
    if (qr == 0) st[r] = make_float2(mx, s);
  }
}

// ---------------------------------------------------------------------------
// K3a: combine per-tile stats -> per-row (max m, 1/l) incl. constant tail
// ---------------------------------------------------------------------------
__global__ __launch_bounds__(256) void combine_k(
    const float* __restrict__ tstats, const float* __restrict__ kq_b,
    float* __restrict__ rs)
{
  const int ridx = blockIdx.x * 256 + threadIdx.x;
  const int q = ridx & 1023, h = (ridx >> 10) & 15, plane = ridx >> 10;
  const int qt = q >> 6;
  const int nkt = min(qt + 2, 16);
  const int Tc = 1024 - (nkt << 6);
  const float2* ts = (const float2*)tstats +
      ((size_t)plane * 151 + (size_t)(qt * (qt + 3) / 2)) * 64 + (q & 63);
  const float kb = kq_b[h];
  float mx = (Tc > 0) ? kb : -3.0e38f;
  for (int kt = 0; kt < nkt; ++kt) mx = fmaxf(mx, ts[(size_t)kt * 64].x);
  float s = (float)Tc * __expf(kb - mx);
  for (int kt = 0; kt < nkt; ++kt) {
    float2 v = ts[(size_t)kt * 64];
    s += v.y * __expf(v.x - mx);
  }
  rs[(size_t)ridx * 2]     = mx;
  rs[(size_t)ridx * 2 + 1] = 1.f / s;
}

// ---------------------------------------------------------------------------
// K3b: PV from stored P tiles. A_o = sum_j (mw[o,j]*rinv_j*exp(mxt_j-m_j))*P_j
// No exp on the P path beyond 2 per kt; barrier-free k-loop.
// ---------------------------------------------------------------------------
__global__ __launch_bounds__(256) void pv_k(
    const bf16* __restrict__ conv_out, const bf16* __restrict__ vT,
    const float* __restrict__ rs, const float* __restrict__ tstats,
    const float* __restrict__ Vtail,
    const float* __restrict__ mix_w, const float* __restrict__ mix_b,
    const float* __restrict__ kq_b,
    const float* __restrict__ dyt_alpha, const float* __restrict__ dyt_w,
    const float* __restrict__ dyt_b, const float* __restrict__ depth_scale,
    bf16* __restrict__ out_attn)
{
  const int qt16 = blockIdx.x, g = blockIdx.y, b = blockIdx.z;
  const int qt = qt16 >> 2;
  const int nkt = min(qt + 2, 16);
  const int Tc = 1024 - (nkt << 6);
  const int tid = threadIdx.x, lane = tid & 63, wid = tid >> 6;
  const int q4 = lane >> 4, n16 = lane & 15;
  const int oo = wid >> 1, kh = wid & 1;
  const int h0 = 2 * g, ho = h0 + oo;
  const int strow = (qt16 & 3) * 16;
  const size_t tbase = (size_t)(qt * (qt + 3) / 2);

  const int qrow = qt16 * 16 + n16;
  const float2 r0 = *(const float2*)(rs + ((((size_t)(b * 16 + h0)     << 10) + qrow) << 1));
  const float2 r1 = *(const float2*)(rs + ((((size_t)(b * 16 + h0 + 1) << 10) + qrow) << 1));
  const float m0 = r0.x, m1 = r1.x;
  const float mwa = mix_w[ho * 2 + 0], mwb = mix_w[ho * 2 + 1];
  const float wa = mwa * r0.y, wb = mwb * r1.y;   // mw * rinv

  const bf16* cb0 = conv_out +
      ((size_t)(b * 16 + h0) * 151 + tbase) * 4096 + strow * 64 + n16 * 64 + q4 * 8;
  const bf16* cb1 = cb0 + (size_t)151 * 4096;
  const float2* ts0 = (const float2*)tstats +
      ((size_t)(b * 16 + h0) * 151 + tbase) * 64 + strow + n16;
  const float2* ts1 = ts0 + (size_t)151 * 64;
  const bf16* vb  = vT + ((size_t)(b * 16 + ho) << 16);

  f32x4 acc[4] = {};
  for (int kt = kh; kt < nkt; kt += 2) {
    const float w0 = wa * __expf(ts0[(size_t)kt * 64].x - m0);
    const float w1 = wb * __expf(ts1[(size_t)kt * 64].x - m1);
    uint4 c0[2], c1[2];
    c0[0] = *(const uint4*)(cb0 + (size_t)kt * 4096);
    c0[1] = *(const uint4*)(cb0 + (size_t)kt * 4096 + 32);
    c1[0] = *(const uint4*)(cb1 + (size_t)kt * 4096);
    c1[1] = *(const uint4*)(cb1 + (size_t)kt * 4096 + 32);
    bf16x8 bv[2][4];
    #pragma unroll
    for (int kk = 0; kk < 2; ++kk)
      #pragma unroll
      for (int ctt = 0; ctt < 4; ++ctt)
        bv[kk][ctt] = *(const bf16x8*)(vb + (size_t)(ctt * 16 + n16) * 1024 + kt * 64 + kk * 32 + q4 * 8);
    #pragma unroll
    for (int kk = 0; kk < 2; ++kk) {
      bf16x8 af;
      const unsigned int* u0 = (const unsigned int*)&c0[kk];
      const unsigned int* u1 = (const unsigned int*)&c1[kk];
      #pragma unroll
      for (int i = 0; i < 4; ++i) {
        float a0 = w0 * bf_lo(u0[i]) + w1 * bf_lo(u1[i]);
        float a1 = w0 * bf_hi(u0[i]) + w1 * bf_hi(u1[i]);
        ((unsigned int*)&af)[i] = cvt_pk_bf16(a0, a1);
      }
      #pragma unroll
      for (int ctt = 0; ctt < 4; ++ctt)
        acc[ctt] = __builtin_amdgcn_mfma_f32_16x16x32_bf16(af, bv[kk][ctt], acc[ctt], 0, 0, 0);
    }
  }

  __shared__ float Pp[2][16][64];
  if (kh == 1) {
    #pragma unroll
    for (int ctt = 0; ctt < 4; ++ctt)
      #pragma unroll
      for (int r = 0; r < 4; ++r)
        Pp[oo][q4 * 4 + r][ctt * 16 + n16] = acc[ctt][r];
  }
  __syncthreads();
  if (kh == 1) return;
  #pragma unroll
  for (int ctt = 0; ctt < 4; ++ctt)
    #pragma unroll
    for (int r = 0; r < 4; ++r)
      acc[ctt][r] += Pp[oo][q4 * 4 + r][ctt * 16 + n16];

  const float kqb0 = kq_b[h0], kqb1 = kq_b[h0 + 1];
  float tw[4];
  #pragma unroll
  for (int r = 0; r < 4; ++r) {
    int qr = qt16 * 16 + q4 * 4 + r;
    float2 s0 = *(const float2*)(rs + ((((size_t)(b * 16 + h0)     << 10) + qr) << 1));
    float2 s1 = *(const float2*)(rs + ((((size_t)(b * 16 + h0 + 1) << 10) + qr) << 1));
    tw[r] = (Tc > 0) ? (mwa * s0.y * __expf(kqb0 - s0.x) +
                        mwb * s1.y * __expf(kqb1 - s1.x)) : 0.f;
  }
  const float mb = mix_b[ho];
  const float alpha = dyt_alpha[0], dsc = depth_scale[0];
  const float* vt = Vtail + (size_t)(b * 16 + ho) * 17 * 64;
  #pragma unroll
  for (int ctt = 0; ctt < 4; ++ctt) {
    int d = ctt * 16 + n16;
    float vtn = vt[(size_t)nkt * 64 + d];
    float vt0 = vt[d];
    float wgt = dyt_w[d], bds = dyt_b[d];
    #pragma unroll
    for (int r = 0; r < 4; ++r) {
      float v = acc[ctt][r] + tw[r] * vtn + mb * vt0;
      float e = __expf(2.f * alpha * v);
      float th = 1.f - 2.f / (e + 1.f);
      float y = (th * wgt + bds) * dsc;
      int qr = qt16 * 16 + q4 * 4 + r;
      out_attn[(((size_t)(b * 1024 + qr)) << 10) + ho * 64 + d] = (bf16)y;
    }
  }
}

// ---------------------------------------------------------------------------
extern "C" void kernel_launch(void* const* d_in, const int* in_sizes, int n_in,
                              void* d_out, int out_size, void* d_ws, size_t ws_size,
                              hipStream_t stream) {
  const float* Q    = (const float*)d_in[0];
  const float* Kx   = (const float*)d_in[1];
  const float* V    = (const float*)d_in[2];
  const float* Wq   = (const float*)d_in[3];
  const float* bq   = (const float*)d_in[4];
  const float* Wk   = (const float*)d_in[5];
  const float* bk   = (const float*)d_in[6];
  const float* Wv   = (const float*)d_in[7];
  const float* bv   = (const float*)d_in[8];
  const float* Wo   = (const float*)d_in[9];
  const float* bo   = (const float*)d_in[10];
  const float* kq_w = (const float*)d_in[11];
  const float* kq_b = (const float*)d_in[12];
  const float* mixw = (const float*)d_in[13];
  const float* mixb = (const float*)d_in[14];
  const float* dyta = (const float*)d_in[15];
  const float* dytw = (const float*)d_in[16];
  const float* dytb = (const float*)d_in[17];
  const float* dsc  = (const float*)d_in[18];

  char* ws = (char*)d_ws;
  bf16* qh     = (bf16*)(ws);                              // 4 MB
  bf16* kh     = (bf16*)(ws + (size_t)(4  << 20));         // 4 MB
  bf16* vT     = (bf16*)(ws + (size_t)(8  << 20));         // 4 MB
  float* tstat = (float*)(ws + (size_t)(12 << 20));        // 2.42 MB (alive thru pv)
  float* Vtail = (float*)(ws + (size_t)(16 << 20));        // 136 KB
  float* Tsum  = (float*)(ws + (size_t)(16 << 20) + (256 << 10)); // 128 KB
  float* rsbuf = (float*)(ws + (size_t)(16 << 20) + (512 << 10)); // 256 KB
  bf16* WtT    = (bf16*)(ws + (size_t)(17 << 20));         // 8 MB (4 planes x 2MB)
  bf16* oat    = (bf16*)(ws + (size_t)(17 << 20));         // 4 MB, aliases Wq/Wk planes (dead after proj)
  bf16* conv   = (bf16*)(ws + (size_t)(25 << 20));         // 39.58 MB (P tiles)
  bf16* Abf    = (bf16*)(ws + (size_t)(50 << 20));         // 12 MB, inside conv region (dead after proj)

  wtr_k<<<dim3(16, 16, 4), 256, 0, stream>>>(Wq, Wk, Wv, Wo, WtT);
  cvt_in_k<<<dim3(3072), 256, 0, stream>>>(Q, Kx, V, Abf);
  proj_gemm_k<<<dim3(16, 32, 3), 256, 0, stream>>>(Abf, WtT, bq, bk, bv, qh);
  vtile_sum_k<<<dim3(16, 16, 2), 64, 0, stream>>>(vT, Tsum);
  vtail_k<<<dim3(16, 2), 64, 0, stream>>>(Tsum, Vtail);
  logits_conv_k<<<dim3(151, 16, 2), 320, 0, stream>>>(qh, kh, kq_w, kq_b, conv, tstat);
  combine_k<<<dim3(128), 256, 0, stream>>>(tstat, kq_b, rsbuf);
  pv_k<<<dim3(64, 8, 2), 256, 0, stream>>>(conv, vT, rsbuf, tstat, Vtail, mixw, mixb, kq_b,
                                           dyta, dytw, dytb, dsc, oat);
  out_gemm_k<<<dim3(16, 32), 256, 0, stream>>>(oat, WtT + ((size_t)3 << 20), bo, (float*)d_out);
}